// Round 2
// baseline (1563.097 us; speedup 1.0000x reference)
//
#include <hip/hip_runtime.h>
#include <math.h>
#include <stdio.h>
#include <stdint.h>

#define GXD 272
#define GYD 112
#define GZD 272
#define NROT 36
#define CCLS (GXD*GZD)     /* 73984 */
#define KSMP 1024          /* NUM_PROPOSAL*OVERSAMPLE */
#define NPROP 256

struct RotTab { float c[NROT]; float s[NROT]; };

// ---------------- threefry2x32 (JAX semantics, 20 rounds) ----------------
__device__ __forceinline__ void threefry2x32(uint32_t k0, uint32_t k1,
                                             uint32_t x0, uint32_t x1,
                                             uint32_t& o0, uint32_t& o1) {
    uint32_t ks2 = k0 ^ k1 ^ 0x1BD11BDAu;
#define TF_ROUND(r) { x0 += x1; x1 = (x1 << (r)) | (x1 >> (32 - (r))); x1 ^= x0; }
    x0 += k0; x1 += k1;
    TF_ROUND(13) TF_ROUND(15) TF_ROUND(26) TF_ROUND(6)
    x0 += k1;  x1 += ks2 + 1u;
    TF_ROUND(17) TF_ROUND(29) TF_ROUND(16) TF_ROUND(24)
    x0 += ks2; x1 += k0 + 2u;
    TF_ROUND(13) TF_ROUND(15) TF_ROUND(26) TF_ROUND(6)
    x0 += k0;  x1 += k1 + 3u;
    TF_ROUND(17) TF_ROUND(29) TF_ROUND(16) TF_ROUND(24)
    x0 += k1;  x1 += ks2 + 4u;
    TF_ROUND(13) TF_ROUND(15) TF_ROUND(26) TF_ROUND(6)
    x0 += ks2; x1 += k0 + 5u;
#undef TF_ROUND
    o0 = x0; o1 = x1;
}

// gumbel = -log(-log(uniform)), with JAX's exact f32 uniform construction.
// f32 logs obtained by rounding double log (matches correctly-rounded libm logf).
__device__ __forceinline__ float gumbel_from_bits(uint32_t b) {
    const float TINY = 1.1754943508222875e-38f; // np.finfo(float32).tiny
    float f = __uint_as_float((b >> 9) | 0x3f800000u) - 1.0f;
    float u = __fadd_rn(__fmul_rn(f, 1.0f), TINY); // u*(maxval-minval)+minval, (1-tiny)==1 in f32
    u = fmaxf(TINY, u);
    float l1 = (float)log((double)u);   // np.log(u) in f32
    float a  = -l1;                      // exact negation
    float l2 = (float)log((double)a);   // np.log(-log u) in f32
    return -l2;
}

// ---------------- K1: hough vote scatter ----------------
__global__ void k_scatter(const float* __restrict__ pc, const float* __restrict__ xyz,
                          const float* __restrict__ scale, const float* __restrict__ prob,
                          const float* __restrict__ corners,
                          float* __restrict__ gobj, float* __restrict__ gscale,
                          int N, RotTab rt) {
    int i = blockIdx.x * blockDim.x + threadIdx.x;
    if (i >= N) return;
    float px = pc[3*i], py = pc[3*i+1], pz = pc[3*i+2];
    float ox = xyz[3*i], oy = xyz[3*i+1], oz = xyz[3*i+2];
    float sx = scale[3*i], sy = scale[3*i+1], sz = scale[3*i+2];
    float w0 = prob[i];
    float c0x = corners[0], c0y = corners[1], c0z = corners[2];

    // y index is rotation-independent
    float ty = __fadd_rn(py, oy);
    float vy = __fadd_rn(__fdiv_rn(__fsub_rn(ty, c0y), 0.03f), 0.5f);
    int iy = (int)floorf(vy);
    if (iy < 0 || iy >= GYD) return;  // all 36 votes have w==0 -> add 0.0 is a no-op

    float wsx = __fmul_rn(w0, sx), wsy = __fmul_rn(w0, sy), wsz = __fmul_rn(w0, sz);

    for (int r = 0; r < NROT; ++r) {
        float c = rt.c[r], s = rt.s[r];
        float rx = __fadd_rn(__fmul_rn(ox, c), __fmul_rn(oz, s));
        float rz = __fadd_rn(__fmul_rn(-ox, s), __fmul_rn(oz, c));
        float tx = __fadd_rn(px, rx);
        float tz = __fadd_rn(pz, rz);
        float vx = __fadd_rn(__fdiv_rn(__fsub_rn(tx, c0x), 0.03f), 0.5f);
        float vz = __fadd_rn(__fdiv_rn(__fsub_rn(tz, c0z), 0.03f), 0.5f);
        int ix = (int)floorf(vx);
        int iz = (int)floorf(vz);
        if (ix < 0 || ix >= GXD || iz < 0 || iz >= GZD) continue;
        int flat = (ix*GYD + iy)*GZD + iz;
        atomicAdd(&gobj[flat], w0);
        atomicAdd(&gscale[3*flat+0], wsx);
        atomicAdd(&gscale[3*flat+1], wsy);
        atomicAdd(&gscale[3*flat+2], wsz);
    }
}

// ---------------- K2: per-(x,z) max/argmax over y; dist, logits ----------------
__global__ void k_colmax(const float* __restrict__ gobj, float* __restrict__ dist,
                         float* __restrict__ logits, int* __restrict__ yidx) {
    int c = blockIdx.x * blockDim.x + threadIdx.x;
    if (c >= CCLS) return;
    int x = c / GZD, z = c % GZD;
    const float* base = gobj + (size_t)x*GYD*GZD + z;
    float m = base[0];
    int mi = 0;
    for (int y = 1; y < GYD; ++y) {
        float v = base[(size_t)y*GZD];
        if (v > m) { m = v; mi = y; }  // strict > => first occurrence
    }
    float sfx = __fadd_rn(m, 1e-7f);
    float d = __fsqrt_rn(sfx);           // power(x, 0.5): correctly-rounded sqrt
    dist[c] = d;
    yidx[c] = mi;
    logits[c] = (float)log((double)__fadd_rn(d, 1e-30f));
}

// ---------------- K3: categorical sampling (gumbel argmax) ----------------
// jax_threefry_partitionable=True (default since JAX 0.4.36) bit derivation:
// element flat index i -> (o0,o1) = threefry(key, hi32(i)=0, lo32(i)=i); bits = o0^o1.
// One block per row k; argmax over columns with first-occurrence tie-break.
__global__ __launch_bounds__(256) void k_sample(const float* __restrict__ logits,
                                                int* __restrict__ samples) {
    int k = blockIdx.x;
    int tid = threadIdx.x;
    uint32_t base = (uint32_t)k * (uint32_t)CCLS;

    float best = -INFINITY;
    int bi = 0;
    for (int c = tid; c < CCLS; c += 256) {
        uint32_t o0, o1;
        threefry2x32(0u, 42u, 0u, base + (uint32_t)c, o0, o1);
        float v = __fadd_rn(gumbel_from_bits(o0 ^ o1), logits[c]);
        if (v > best) { best = v; bi = c; }  // strict > => smallest c among this thread
    }

    __shared__ float sv[256];
    __shared__ int   si[256];
    sv[tid] = best; si[tid] = bi; __syncthreads();
    for (int off = 128; off > 0; off >>= 1) {
        if (tid < off) {
            float v2 = sv[tid+off]; int i2 = si[tid+off];
            if (v2 > sv[tid] || (v2 == sv[tid] && i2 < si[tid])) { sv[tid] = v2; si[tid] = i2; }
        }
        __syncthreads();
    }
    if (tid == 0) samples[k] = si[0];
}

// ---------------- K4: per-sample world loc, scale lookup, keep flag ----------------
__global__ void k_post(const float* __restrict__ gobj, const float* __restrict__ gscale,
                       const int* __restrict__ yidx, const int* __restrict__ samples,
                       const float* __restrict__ corners, const float* __restrict__ vp, int M,
                       float* __restrict__ world, float* __restrict__ scv, int* __restrict__ keep) {
    int k = blockIdx.x * blockDim.x + threadIdx.x;
    if (k >= KSMP) return;
    int s = samples[k];
    int xi = s / GZD, zi = s % GZD;
    int yi = yidx[s];
    float wx = __fadd_rn(__fmul_rn((float)xi, 0.03f), corners[0]);
    float wy = __fadd_rn(__fmul_rn((float)yi, 0.03f), corners[1]);
    float wz = __fadd_rn(__fmul_rn((float)zi, 0.03f), corners[2]);
    world[3*k] = wx; world[3*k+1] = wy; world[3*k+2] = wz;

    size_t flat = ((size_t)xi*GYD + yi)*GZD + zi;
    float go = __fadd_rn(gobj[flat], 1e-7f);
    scv[3*k+0] = __fdiv_rn(gscale[3*flat+0], go);
    scv[3*k+1] = __fdiv_rn(gscale[3*flat+1], go);
    scv[3*k+2] = __fdiv_rn(gscale[3*flat+2], go);

    float dmin = INFINITY;
    for (int j = 0; j < M; ++j) {
        float dx = __fsub_rn(wx, vp[3*j]);
        float dy = __fsub_rn(wy, vp[3*j+1]);
        float dz = __fsub_rn(wz, vp[3*j+2]);
        float sq = __fadd_rn(__fadd_rn(__fmul_rn(dx,dx), __fmul_rn(dy,dy)), __fmul_rn(dz,dz));
        float d = __fsqrt_rn(sq);
        dmin = fminf(dmin, d);
    }
    keep[k] = (dmin < 0.3f) ? 1 : 0;
}

// ---------------- K5: stable 0/1 selection + output write ----------------
__global__ __launch_bounds__(256) void k_select(const float* __restrict__ world,
                                                const float* __restrict__ scv,
                                                const int* __restrict__ keep,
                                                float* __restrict__ out) {
    __shared__ int kp[KSMP];
    __shared__ int sel[NPROP];
    int tid = threadIdx.x;
    for (int j = tid; j < KSMP; j += 256) kp[j] = keep[j];
    __syncthreads();
    if (tid == 0) {
        int any = 0;
        for (int j = 0; j < KSMP; ++j) any |= kp[j];
        int cnt = 0;
        if (any) {
            for (int j = 0; j < KSMP && cnt < NPROP; ++j) if (kp[j])  sel[cnt++] = j;
            for (int j = 0; j < KSMP && cnt < NPROP; ++j) if (!kp[j]) sel[cnt++] = j;
        } else {
            for (int j = 0; j < NPROP; ++j) sel[j] = j;  // argsort(zeros) stable = identity
        }
    }
    __syncthreads();
    if (tid < NPROP) {
        int sidx = sel[tid];
        out[3*tid+0] = world[3*sidx+0];
        out[3*tid+1] = world[3*sidx+1];
        out[3*tid+2] = world[3*sidx+2];
        out[3*NPROP + tid] = 0.0f;                 // probs
        out[4*NPROP + 3*tid + 0] = scv[3*sidx+0];
        out[4*NPROP + 3*tid + 1] = scv[3*sidx+1];
        out[4*NPROP + 3*tid + 2] = scv[3*sidx+2];
    }
}

extern "C" void kernel_launch(void* const* d_in, const int* in_sizes, int n_in,
                              void* d_out, int out_size, void* d_ws, size_t ws_size,
                              hipStream_t stream) {
    const float* pc      = (const float*)d_in[0];
    const float* xyz     = (const float*)d_in[1];
    const float* scale   = (const float*)d_in[2];
    const float* prob    = (const float*)d_in[3];
    const float* corners = (const float*)d_in[4];
    const float* vp      = (const float*)d_in[5];
    int N = in_sizes[0] / 3;
    int M = in_sizes[5] / 3;

    const size_t G = (size_t)GXD * GYD * GZD;  // 8,286,208
    float* gobj   = (float*)d_ws;
    float* gscale = gobj + G;
    float* logits = gscale + 3*G;
    float* dist   = logits + CCLS;
    int*   yidx   = (int*)(dist + CCLS);
    int*   samples= yidx + CCLS;
    float* world  = (float*)(samples + KSMP);
    float* scv    = world + 3*KSMP;
    int*   keep   = (int*)(scv + 3*KSMP);
    size_t need = (size_t)((char*)(keep + KSMP) - (char*)d_ws);
    if (ws_size < need) {
        fprintf(stderr, "kernel_launch: ws_size %zu < needed %zu\n", ws_size, need);
        return;
    }

    // zero grid_obj + grid_scale (contiguous 4*G floats)
    hipMemsetAsync(gobj, 0, 4*G*sizeof(float), stream);

    // rotation table: f32 theta chain exactly as reference, cos/sin in double -> f32
    RotTab rt;
    const float twopi = (float)(2.0 * M_PI);
    for (int r = 0; r < NROT; ++r) {
        float th = (twopi * (float)r) / 36.0f;
        rt.c[r] = (float)cos((double)th);
        rt.s[r] = (float)sin((double)th);
    }

    k_scatter<<<(N + 255) / 256, 256, 0, stream>>>(pc, xyz, scale, prob, corners, gobj, gscale, N, rt);
    k_colmax<<<(CCLS + 255) / 256, 256, 0, stream>>>(gobj, dist, logits, yidx);
    k_sample<<<KSMP, 256, 0, stream>>>(logits, samples);
    k_post<<<(KSMP + 255) / 256, 256, 0, stream>>>(gobj, gscale, yidx, samples, corners, vp, M, world, scv, keep);
    k_select<<<1, 256, 0, stream>>>(world, scv, keep, (float*)d_out);
}

// Round 3
// 1200.881 us; speedup vs baseline: 1.3016x; 1.3016x over previous
//
#include <hip/hip_runtime.h>
#include <math.h>
#include <stdio.h>
#include <stdint.h>

#define GXD 272
#define GYD 112
#define GZD 272
#define NROT 36
#define CCLS (GXD*GZD)     /* 73984 */
#define KSMP 1024          /* NUM_PROPOSAL*OVERSAMPLE */
#define NPROP 256

struct RotTab { float c[NROT]; float s[NROT]; };

// ---------------- threefry2x32 (JAX semantics, 20 rounds) ----------------
__device__ __forceinline__ void threefry2x32(uint32_t k0, uint32_t k1,
                                             uint32_t x0, uint32_t x1,
                                             uint32_t& o0, uint32_t& o1) {
    uint32_t ks2 = k0 ^ k1 ^ 0x1BD11BDAu;
#define TF_ROUND(r) { x0 += x1; x1 = (x1 << (r)) | (x1 >> (32 - (r))); x1 ^= x0; }
    x0 += k0; x1 += k1;
    TF_ROUND(13) TF_ROUND(15) TF_ROUND(26) TF_ROUND(6)
    x0 += k1;  x1 += ks2 + 1u;
    TF_ROUND(17) TF_ROUND(29) TF_ROUND(16) TF_ROUND(24)
    x0 += ks2; x1 += k0 + 2u;
    TF_ROUND(13) TF_ROUND(15) TF_ROUND(26) TF_ROUND(6)
    x0 += k0;  x1 += k1 + 3u;
    TF_ROUND(17) TF_ROUND(29) TF_ROUND(16) TF_ROUND(24)
    x0 += k1;  x1 += ks2 + 4u;
    TF_ROUND(13) TF_ROUND(15) TF_ROUND(26) TF_ROUND(6)
    x0 += ks2; x1 += k0 + 5u;
#undef TF_ROUND
    o0 = x0; o1 = x1;
}

__device__ __forceinline__ float uniform_from_bits(uint32_t b) {
    const float TINY = 1.1754943508222875e-38f; // np.finfo(float32).tiny
    float f = __uint_as_float((b >> 9) | 0x3f800000u) - 1.0f;
    float u = __fadd_rn(__fmul_rn(f, 1.0f), TINY);
    return fmaxf(TINY, u);
}

// gumbel = -log(-log(u)); f32 logs via double rounding (== correctly-rounded logf)
__device__ __forceinline__ float gumbel_from_u(float u) {
    float l1 = (float)log((double)u);
    float l2 = (float)log((double)(-l1));
    return -l2;
}

// ---------------- K1: hough vote scatter — one thread per (point, rotation) ----------------
__global__ __launch_bounds__(256) void k_scatter(const float* __restrict__ pc, const float* __restrict__ xyz,
                          const float* __restrict__ scale, const float* __restrict__ prob,
                          const float* __restrict__ corners,
                          float* __restrict__ gobj, float* __restrict__ gscale,
                          int N, RotTab rt) {
    int i = blockIdx.x * blockDim.x + threadIdx.x;
    int r = blockIdx.y;
    if (i >= N) return;
    float px = pc[3*i], py = pc[3*i+1], pz = pc[3*i+2];
    float ox = xyz[3*i], oy = xyz[3*i+1], oz = xyz[3*i+2];
    float w0 = prob[i];
    float c0x = corners[0], c0y = corners[1], c0z = corners[2];

    // y index is rotation-independent
    float ty = __fadd_rn(py, oy);
    float vy = __fadd_rn(__fdiv_rn(__fsub_rn(ty, c0y), 0.03f), 0.5f);
    int iy = (int)floorf(vy);
    if (iy < 0 || iy >= GYD) return;  // weight 0 -> no-op adds

    float c = rt.c[r], s = rt.s[r];
    float rx = __fadd_rn(__fmul_rn(ox, c), __fmul_rn(oz, s));
    float rz = __fadd_rn(__fmul_rn(-ox, s), __fmul_rn(oz, c));
    float tx = __fadd_rn(px, rx);
    float tz = __fadd_rn(pz, rz);
    float vx = __fadd_rn(__fdiv_rn(__fsub_rn(tx, c0x), 0.03f), 0.5f);
    float vz = __fadd_rn(__fdiv_rn(__fsub_rn(tz, c0z), 0.03f), 0.5f);
    int ix = (int)floorf(vx);
    int iz = (int)floorf(vz);
    if (ix < 0 || ix >= GXD || iz < 0 || iz >= GZD) return;
    int flat = (ix*GYD + iy)*GZD + iz;
    atomicAdd(&gobj[flat], w0);
    atomicAdd(&gscale[3*flat+0], __fmul_rn(w0, scale[3*i]));
    atomicAdd(&gscale[3*flat+1], __fmul_rn(w0, scale[3*i+1]));
    atomicAdd(&gscale[3*flat+2], __fmul_rn(w0, scale[3*i+2]));
}

// ---------------- K2: per-(x,z) max/argmax over y; dist, logits; sum(dist) ----------------
__global__ __launch_bounds__(256) void k_colmax(const float* __restrict__ gobj, float* __restrict__ dist,
                         float* __restrict__ logits, int* __restrict__ yidx,
                         float* __restrict__ sumdist) {
    int c = blockIdx.x * blockDim.x + threadIdx.x;
    float d = 0.0f;
    if (c < CCLS) {
        int x = c / GZD, z = c % GZD;
        const float* base = gobj + (size_t)x*GYD*GZD + z;
        float m = base[0];
        int mi = 0;
        for (int y = 1; y < GYD; ++y) {
            float v = base[(size_t)y*GZD];
            if (v > m) { m = v; mi = y; }  // strict > => first occurrence
        }
        float sfx = __fadd_rn(m, 1e-7f);
        d = __fsqrt_rn(sfx);
        dist[c] = d;
        yidx[c] = mi;
        logits[c] = (float)log((double)__fadd_rn(d, 1e-30f));
    }
    // block-reduce d into sumdist (heuristic only — order-insensitive use)
    __shared__ float sred[256];
    int tid = threadIdx.x;
    sred[tid] = d; __syncthreads();
    for (int off = 128; off > 0; off >>= 1) {
        if (tid < off) sred[tid] += sred[tid+off];
        __syncthreads();
    }
    if (tid == 0) atomicAdd(sumdist, sred[0]);
}

// ---------------- K2b: per-column u-threshold for pruning ----------------
// survivor condition v = gumbel(u) + L > B0  <=>  u > exp(-exp(L - B0)).
// Computed in double with 0.05 margin in B0 and a downward nudge -> can only
// over-include (extra survivors get exact evaluation), never exclude the max.
__global__ __launch_bounds__(256) void k_thresh(const float* __restrict__ logits,
                                                const float* __restrict__ sumdist,
                                                float* __restrict__ u_th) {
    int c = blockIdx.x * blockDim.x + threadIdx.x;
    if (c >= CCLS) return;
    double B0 = log((double)*sumdist) - 3.0;
    double t = exp(-exp((double)logits[c] - (B0 - 0.05)));
    u_th[c] = (float)(t * (1.0 - 1e-9));
}

// ---------------- K3: categorical sampling (pruned gumbel argmax) ----------------
__global__ __launch_bounds__(256) void k_sample(const float* __restrict__ logits,
                                                const float* __restrict__ u_th,
                                                int* __restrict__ samples) {
    int k = blockIdx.x;
    int tid = threadIdx.x;
    uint32_t base = (uint32_t)k * (uint32_t)CCLS;

    float best = -INFINITY;
    int bi = 0x7fffffff;
    for (int c = tid; c < CCLS; c += 256) {
        uint32_t o0, o1;
        threefry2x32(0u, 42u, 0u, base + (uint32_t)c, o0, o1);
        float u = uniform_from_bits(o0 ^ o1);
        if (u > u_th[c]) {   // rare (~20/row over all 256 threads)
            float v = __fadd_rn(gumbel_from_u(u), logits[c]);
            if (v > best) { best = v; bi = c; }
        }
    }

    __shared__ float sv[256];
    __shared__ int   si[256];
    sv[tid] = best; si[tid] = bi; __syncthreads();
    for (int off = 128; off > 0; off >>= 1) {
        if (tid < off) {
            float v2 = sv[tid+off]; int i2 = si[tid+off];
            if (v2 > sv[tid] || (v2 == sv[tid] && i2 < si[tid])) { sv[tid] = v2; si[tid] = i2; }
        }
        __syncthreads();
    }

    if (sv[0] == -INFINITY) {
        // fallback: no survivor in this row (P ~ exp(-e^3) ~ 0) — exact full scan
        best = -INFINITY; bi = 0x7fffffff;
        for (int c = tid; c < CCLS; c += 256) {
            uint32_t o0, o1;
            threefry2x32(0u, 42u, 0u, base + (uint32_t)c, o0, o1);
            float v = __fadd_rn(gumbel_from_u(uniform_from_bits(o0 ^ o1)), logits[c]);
            if (v > best) { best = v; bi = c; }
        }
        __syncthreads();
        sv[tid] = best; si[tid] = bi; __syncthreads();
        for (int off = 128; off > 0; off >>= 1) {
            if (tid < off) {
                float v2 = sv[tid+off]; int i2 = si[tid+off];
                if (v2 > sv[tid] || (v2 == sv[tid] && i2 < si[tid])) { sv[tid] = v2; si[tid] = i2; }
            }
            __syncthreads();
        }
    }
    if (tid == 0) samples[k] = si[0];
}

// ---------------- K4: per-sample world loc, scale lookup, keep flag ----------------
__global__ void k_post(const float* __restrict__ gobj, const float* __restrict__ gscale,
                       const int* __restrict__ yidx, const int* __restrict__ samples,
                       const float* __restrict__ corners, const float* __restrict__ vp, int M,
                       float* __restrict__ world, float* __restrict__ scv, int* __restrict__ keep) {
    int k = blockIdx.x * blockDim.x + threadIdx.x;
    if (k >= KSMP) return;
    int s = samples[k];
    int xi = s / GZD, zi = s % GZD;
    int yi = yidx[s];
    float wx = __fadd_rn(__fmul_rn((float)xi, 0.03f), corners[0]);
    float wy = __fadd_rn(__fmul_rn((float)yi, 0.03f), corners[1]);
    float wz = __fadd_rn(__fmul_rn((float)zi, 0.03f), corners[2]);
    world[3*k] = wx; world[3*k+1] = wy; world[3*k+2] = wz;

    size_t flat = ((size_t)xi*GYD + yi)*GZD + zi;
    float go = __fadd_rn(gobj[flat], 1e-7f);
    scv[3*k+0] = __fdiv_rn(gscale[3*flat+0], go);
    scv[3*k+1] = __fdiv_rn(gscale[3*flat+1], go);
    scv[3*k+2] = __fdiv_rn(gscale[3*flat+2], go);

    float dmin = INFINITY;
    for (int j = 0; j < M; ++j) {
        float dx = __fsub_rn(wx, vp[3*j]);
        float dy = __fsub_rn(wy, vp[3*j+1]);
        float dz = __fsub_rn(wz, vp[3*j+2]);
        float sq = __fadd_rn(__fadd_rn(__fmul_rn(dx,dx), __fmul_rn(dy,dy)), __fmul_rn(dz,dz));
        float d = __fsqrt_rn(sq);
        dmin = fminf(dmin, d);
    }
    keep[k] = (dmin < 0.3f) ? 1 : 0;
}

// ---------------- K5: stable 0/1 selection + output write ----------------
__global__ __launch_bounds__(256) void k_select(const float* __restrict__ world,
                                                const float* __restrict__ scv,
                                                const int* __restrict__ keep,
                                                float* __restrict__ out) {
    __shared__ int kp[KSMP];
    __shared__ int sel[NPROP];
    int tid = threadIdx.x;
    for (int j = tid; j < KSMP; j += 256) kp[j] = keep[j];
    __syncthreads();
    if (tid == 0) {
        int any = 0;
        for (int j = 0; j < KSMP; ++j) any |= kp[j];
        int cnt = 0;
        if (any) {
            for (int j = 0; j < KSMP && cnt < NPROP; ++j) if (kp[j])  sel[cnt++] = j;
            for (int j = 0; j < KSMP && cnt < NPROP; ++j) if (!kp[j]) sel[cnt++] = j;
        } else {
            for (int j = 0; j < NPROP; ++j) sel[j] = j;  // argsort(zeros) stable = identity
        }
    }
    __syncthreads();
    if (tid < NPROP) {
        int sidx = sel[tid];
        out[3*tid+0] = world[3*sidx+0];
        out[3*tid+1] = world[3*sidx+1];
        out[3*tid+2] = world[3*sidx+2];
        out[3*NPROP + tid] = 0.0f;                 // probs
        out[4*NPROP + 3*tid + 0] = scv[3*sidx+0];
        out[4*NPROP + 3*tid + 1] = scv[3*sidx+1];
        out[4*NPROP + 3*tid + 2] = scv[3*sidx+2];
    }
}

extern "C" void kernel_launch(void* const* d_in, const int* in_sizes, int n_in,
                              void* d_out, int out_size, void* d_ws, size_t ws_size,
                              hipStream_t stream) {
    const float* pc      = (const float*)d_in[0];
    const float* xyz     = (const float*)d_in[1];
    const float* scale   = (const float*)d_in[2];
    const float* prob    = (const float*)d_in[3];
    const float* corners = (const float*)d_in[4];
    const float* vp      = (const float*)d_in[5];
    int N = in_sizes[0] / 3;
    int M = in_sizes[5] / 3;

    const size_t G = (size_t)GXD * GYD * GZD;  // 8,286,208
    float* gobj    = (float*)d_ws;
    float* gscale  = gobj + G;
    float* sumdist = gscale + 3*G;      // 1 float, inside the zeroed span
    float* logits  = sumdist + 1;
    float* dist    = logits + CCLS;
    float* u_th    = dist + CCLS;
    int*   yidx    = (int*)(u_th + CCLS);
    int*   samples = yidx + CCLS;
    float* world   = (float*)(samples + KSMP);
    float* scv     = world + 3*KSMP;
    int*   keep    = (int*)(scv + 3*KSMP);
    size_t need = (size_t)((char*)(keep + KSMP) - (char*)d_ws);
    if (ws_size < need) {
        fprintf(stderr, "kernel_launch: ws_size %zu < needed %zu\n", ws_size, need);
        return;
    }

    // zero grid_obj + grid_scale + sumdist (contiguous)
    hipMemsetAsync(gobj, 0, (4*G + 1)*sizeof(float), stream);

    // rotation table: f32 theta chain exactly as reference, cos/sin in double -> f32
    RotTab rt;
    const float twopi = (float)(2.0 * M_PI);
    for (int r = 0; r < NROT; ++r) {
        float th = (twopi * (float)r) / 36.0f;
        rt.c[r] = (float)cos((double)th);
        rt.s[r] = (float)sin((double)th);
    }

    dim3 sgrid((N + 255) / 256, NROT);
    k_scatter<<<sgrid, 256, 0, stream>>>(pc, xyz, scale, prob, corners, gobj, gscale, N, rt);
    k_colmax<<<(CCLS + 255) / 256, 256, 0, stream>>>(gobj, dist, logits, yidx, sumdist);
    k_thresh<<<(CCLS + 255) / 256, 256, 0, stream>>>(logits, sumdist, u_th);
    k_sample<<<KSMP, 256, 0, stream>>>(logits, u_th, samples);
    k_post<<<(KSMP + 255) / 256, 256, 0, stream>>>(gobj, gscale, yidx, samples, corners, vp, M, world, scv, keep);
    k_select<<<1, 256, 0, stream>>>(world, scv, keep, (float*)d_out);
}

// Round 4
// 696.500 us; speedup vs baseline: 2.2442x; 1.7242x over previous
//
#include <hip/hip_runtime.h>
#include <math.h>
#include <stdio.h>
#include <stdint.h>

#define GXD 272
#define GYD 112
#define GZD 272
#define NROT 36
#define CCLS (GXD*GZD)     /* 73984 */
#define KSMP 1024          /* NUM_PROPOSAL*OVERSAMPLE */
#define NPROP 256
#define HSLOTS 2048        /* sampled-cell hash table slots (load factor <= 0.5) */

struct RotTab { float c[NROT]; float s[NROT]; };

__device__ __forceinline__ uint32_t cell_hash(int flat) {
    return ((uint32_t)flat * 2654435761u) >> 21;  // top 11 bits -> 0..2047
}

// ---------------- threefry2x32 (JAX semantics, 20 rounds) ----------------
__device__ __forceinline__ void threefry2x32(uint32_t k0, uint32_t k1,
                                             uint32_t x0, uint32_t x1,
                                             uint32_t& o0, uint32_t& o1) {
    uint32_t ks2 = k0 ^ k1 ^ 0x1BD11BDAu;
#define TF_ROUND(r) { x0 += x1; x1 = (x1 << (r)) | (x1 >> (32 - (r))); x1 ^= x0; }
    x0 += k0; x1 += k1;
    TF_ROUND(13) TF_ROUND(15) TF_ROUND(26) TF_ROUND(6)
    x0 += k1;  x1 += ks2 + 1u;
    TF_ROUND(17) TF_ROUND(29) TF_ROUND(16) TF_ROUND(24)
    x0 += ks2; x1 += k0 + 2u;
    TF_ROUND(13) TF_ROUND(15) TF_ROUND(26) TF_ROUND(6)
    x0 += k0;  x1 += k1 + 3u;
    TF_ROUND(17) TF_ROUND(29) TF_ROUND(16) TF_ROUND(24)
    x0 += k1;  x1 += ks2 + 4u;
    TF_ROUND(13) TF_ROUND(15) TF_ROUND(26) TF_ROUND(6)
    x0 += ks2; x1 += k0 + 5u;
#undef TF_ROUND
    o0 = x0; o1 = x1;
}

__device__ __forceinline__ float uniform_from_bits(uint32_t b) {
    const float TINY = 1.1754943508222875e-38f; // np.finfo(float32).tiny
    float f = __uint_as_float((b >> 9) | 0x3f800000u) - 1.0f;
    float u = __fadd_rn(__fmul_rn(f, 1.0f), TINY);
    return fmaxf(TINY, u);
}

// gumbel = -log(-log(u)); f32 logs via double rounding (== correctly-rounded logf)
__device__ __forceinline__ float gumbel_from_u(float u) {
    float l1 = (float)log((double)u);
    float l2 = (float)log((double)(-l1));
    return -l2;
}

// shared vote-cell computation (must stay bit-identical across passes)
__device__ __forceinline__ bool vote_cell(float px, float py, float pz,
                                          float ox, float oy, float oz,
                                          float c, float s,
                                          float c0x, float c0y, float c0z,
                                          int& flat) {
    float ty = __fadd_rn(py, oy);
    float vy = __fadd_rn(__fdiv_rn(__fsub_rn(ty, c0y), 0.03f), 0.5f);
    int iy = (int)floorf(vy);
    if (iy < 0 || iy >= GYD) return false;
    float rx = __fadd_rn(__fmul_rn(ox, c), __fmul_rn(oz, s));
    float rz = __fadd_rn(__fmul_rn(-ox, s), __fmul_rn(oz, c));
    float tx = __fadd_rn(px, rx);
    float tz = __fadd_rn(pz, rz);
    float vx = __fadd_rn(__fdiv_rn(__fsub_rn(tx, c0x), 0.03f), 0.5f);
    float vz = __fadd_rn(__fdiv_rn(__fsub_rn(tz, c0z), 0.03f), 0.5f);
    int ix = (int)floorf(vx);
    int iz = (int)floorf(vz);
    if (ix < 0 || ix >= GXD || iz < 0 || iz >= GZD) return false;
    flat = (ix*GYD + iy)*GZD + iz;
    return true;
}

// ---------------- K1: hough vote scatter, gobj ONLY (1 atomic/vote) ----------------
__global__ __launch_bounds__(256) void k_scatter(const float* __restrict__ pc, const float* __restrict__ xyz,
                          const float* __restrict__ prob, const float* __restrict__ corners,
                          float* __restrict__ gobj, int N, RotTab rt) {
    int i = blockIdx.x * blockDim.x + threadIdx.x;
    int r = blockIdx.y;
    if (i >= N) return;
    int flat;
    if (!vote_cell(pc[3*i], pc[3*i+1], pc[3*i+2], xyz[3*i], xyz[3*i+1], xyz[3*i+2],
                   rt.c[r], rt.s[r], corners[0], corners[1], corners[2], flat)) return;
    atomicAdd(&gobj[flat], prob[i]);
}

// ---------------- K2: per-(x,z) max/argmax over y; logits; sum(dist) ----------------
__global__ __launch_bounds__(256) void k_colmax(const float* __restrict__ gobj,
                         float* __restrict__ logits, int* __restrict__ yidx,
                         float* __restrict__ sumdist) {
    int c = blockIdx.x * blockDim.x + threadIdx.x;
    float d = 0.0f;
    if (c < CCLS) {
        int x = c / GZD, z = c % GZD;
        const float* base = gobj + (size_t)x*GYD*GZD + z;
        float m = base[0];
        int mi = 0;
        for (int y = 1; y < GYD; ++y) {
            float v = base[(size_t)y*GZD];
            if (v > m) { m = v; mi = y; }  // strict > => first occurrence
        }
        d = __fsqrt_rn(__fadd_rn(m, 1e-7f));
        yidx[c] = mi;
        logits[c] = (float)log((double)__fadd_rn(d, 1e-30f));
    }
    __shared__ float sred[256];
    int tid = threadIdx.x;
    sred[tid] = d; __syncthreads();
    for (int off = 128; off > 0; off >>= 1) {
        if (tid < off) sred[tid] += sred[tid+off];
        __syncthreads();
    }
    if (tid == 0) atomicAdd(sumdist, sred[0]);
}

// ---------------- K2b: per-column u-threshold for pruning ----------------
__global__ __launch_bounds__(256) void k_thresh(const float* __restrict__ logits,
                                                const float* __restrict__ sumdist,
                                                float* __restrict__ u_th) {
    int c = blockIdx.x * blockDim.x + threadIdx.x;
    if (c >= CCLS) return;
    double B0 = log((double)*sumdist) - 3.0;
    double t = exp(-exp((double)logits[c] - (B0 - 0.05)));
    u_th[c] = (float)(t * (1.0 - 1e-9));
}

// ---------------- K3: categorical sampling (pruned gumbel argmax) ----------------
__global__ __launch_bounds__(256) void k_sample(const float* __restrict__ logits,
                                                const float* __restrict__ u_th,
                                                int* __restrict__ samples) {
    int k = blockIdx.x;
    int tid = threadIdx.x;
    uint32_t base = (uint32_t)k * (uint32_t)CCLS;

    float best = -INFINITY;
    int bi = 0x7fffffff;
    for (int c = tid; c < CCLS; c += 256) {
        uint32_t o0, o1;
        threefry2x32(0u, 42u, 0u, base + (uint32_t)c, o0, o1);
        float u = uniform_from_bits(o0 ^ o1);
        if (u > u_th[c]) {   // rare (~20/row total)
            float v = __fadd_rn(gumbel_from_u(u), logits[c]);
            if (v > best) { best = v; bi = c; }
        }
    }

    __shared__ float sv[256];
    __shared__ int   si[256];
    sv[tid] = best; si[tid] = bi; __syncthreads();
    for (int off = 128; off > 0; off >>= 1) {
        if (tid < off) {
            float v2 = sv[tid+off]; int i2 = si[tid+off];
            if (v2 > sv[tid] || (v2 == sv[tid] && i2 < si[tid])) { sv[tid] = v2; si[tid] = i2; }
        }
        __syncthreads();
    }

    if (sv[0] == -INFINITY) {
        // fallback (P ~ exp(-e^3)): exact full scan
        best = -INFINITY; bi = 0x7fffffff;
        for (int c = tid; c < CCLS; c += 256) {
            uint32_t o0, o1;
            threefry2x32(0u, 42u, 0u, base + (uint32_t)c, o0, o1);
            float v = __fadd_rn(gumbel_from_u(uniform_from_bits(o0 ^ o1)), logits[c]);
            if (v > best) { best = v; bi = c; }
        }
        __syncthreads();
        sv[tid] = best; si[tid] = bi; __syncthreads();
        for (int off = 128; off > 0; off >>= 1) {
            if (tid < off) {
                float v2 = sv[tid+off]; int i2 = si[tid+off];
                if (v2 > sv[tid] || (v2 == sv[tid] && i2 < si[tid])) { sv[tid] = v2; si[tid] = i2; }
            }
            __syncthreads();
        }
    }
    if (tid == 0) samples[k] = si[0];
}

// ---------------- K3b: build sampled-cell hash table (single block) ----------------
__global__ __launch_bounds__(256) void k_build_table(const int* __restrict__ samples,
                                                     const int* __restrict__ yidx,
                                                     int* __restrict__ hkeys,
                                                     float* __restrict__ gsmall) {
    int tid = threadIdx.x;
    for (int j = tid; j < HSLOTS; j += 256) hkeys[j] = -1;
    for (int j = tid; j < 3*HSLOTS; j += 256) gsmall[j] = 0.0f;
    __syncthreads();
    for (int k = tid; k < KSMP; k += 256) {
        int s = samples[k];
        int xi = s / GZD, zi = s % GZD;
        int yi = yidx[s];
        int flat = (xi*GYD + yi)*GZD + zi;
        uint32_t h = cell_hash(flat);
        for (;;) {
            int prev = atomicCAS(&hkeys[h], -1, flat);
            if (prev == -1 || prev == flat) break;
            h = (h + 1) & (HSLOTS - 1);
        }
    }
}

// ---------------- K3c: replay votes, accumulate scale sums at sampled cells ----------------
__global__ __launch_bounds__(256) void k_scale_scatter(const float* __restrict__ pc, const float* __restrict__ xyz,
                          const float* __restrict__ scale, const float* __restrict__ prob,
                          const float* __restrict__ corners,
                          const int* __restrict__ hkeys, float* __restrict__ gsmall,
                          int N, RotTab rt) {
    __shared__ int lk[HSLOTS];
    for (int j = threadIdx.x; j < HSLOTS; j += 256) lk[j] = hkeys[j];
    __syncthreads();
    int i = blockIdx.x * blockDim.x + threadIdx.x;
    int r = blockIdx.y;
    if (i >= N) return;
    int flat;
    if (!vote_cell(pc[3*i], pc[3*i+1], pc[3*i+2], xyz[3*i], xyz[3*i+1], xyz[3*i+2],
                   rt.c[r], rt.s[r], corners[0], corners[1], corners[2], flat)) return;
    uint32_t h = cell_hash(flat);
    int slot = -1;
    for (;;) {
        int key = lk[h];
        if (key == flat) { slot = (int)h; break; }
        if (key == -1) break;
        h = (h + 1) & (HSLOTS - 1);
    }
    if (slot < 0) return;
    float w0 = prob[i];
    atomicAdd(&gsmall[3*slot+0], __fmul_rn(w0, scale[3*i]));
    atomicAdd(&gsmall[3*slot+1], __fmul_rn(w0, scale[3*i+1]));
    atomicAdd(&gsmall[3*slot+2], __fmul_rn(w0, scale[3*i+2]));
}

// ---------------- K4: per-sample world loc, scale lookup, keep flag ----------------
__global__ __launch_bounds__(256) void k_post(const float* __restrict__ gobj,
                       const int* __restrict__ hkeys, const float* __restrict__ gsmall,
                       const int* __restrict__ yidx, const int* __restrict__ samples,
                       const float* __restrict__ corners, const float* __restrict__ vp, int M,
                       float* __restrict__ world, float* __restrict__ scv, int* __restrict__ keep) {
    int k = blockIdx.x * blockDim.x + threadIdx.x;
    if (k >= KSMP) return;
    int s = samples[k];
    int xi = s / GZD, zi = s % GZD;
    int yi = yidx[s];
    float wx = __fadd_rn(__fmul_rn((float)xi, 0.03f), corners[0]);
    float wy = __fadd_rn(__fmul_rn((float)yi, 0.03f), corners[1]);
    float wz = __fadd_rn(__fmul_rn((float)zi, 0.03f), corners[2]);
    world[3*k] = wx; world[3*k+1] = wy; world[3*k+2] = wz;

    int flat = (xi*GYD + yi)*GZD + zi;
    uint32_t h = cell_hash(flat);
    while (hkeys[h] != flat) h = (h + 1) & (HSLOTS - 1);  // guaranteed present
    float go = __fadd_rn(gobj[flat], 1e-7f);
    scv[3*k+0] = __fdiv_rn(gsmall[3*h+0], go);
    scv[3*k+1] = __fdiv_rn(gsmall[3*h+1], go);
    scv[3*k+2] = __fdiv_rn(gsmall[3*h+2], go);

    float dmin = INFINITY;
    for (int j = 0; j < M; ++j) {
        float dx = __fsub_rn(wx, vp[3*j]);
        float dy = __fsub_rn(wy, vp[3*j+1]);
        float dz = __fsub_rn(wz, vp[3*j+2]);
        float sq = __fadd_rn(__fadd_rn(__fmul_rn(dx,dx), __fmul_rn(dy,dy)), __fmul_rn(dz,dz));
        dmin = fminf(dmin, __fsqrt_rn(sq));
    }
    keep[k] = (dmin < 0.3f) ? 1 : 0;
}

// ---------------- K5: stable 0/1 selection + output write ----------------
__global__ __launch_bounds__(256) void k_select(const float* __restrict__ world,
                                                const float* __restrict__ scv,
                                                const int* __restrict__ keep,
                                                float* __restrict__ out) {
    __shared__ int kp[KSMP];
    __shared__ int sel[NPROP];
    int tid = threadIdx.x;
    for (int j = tid; j < KSMP; j += 256) kp[j] = keep[j];
    __syncthreads();
    if (tid == 0) {
        int any = 0;
        for (int j = 0; j < KSMP; ++j) any |= kp[j];
        int cnt = 0;
        if (any) {
            for (int j = 0; j < KSMP && cnt < NPROP; ++j) if (kp[j])  sel[cnt++] = j;
            for (int j = 0; j < KSMP && cnt < NPROP; ++j) if (!kp[j]) sel[cnt++] = j;
        } else {
            for (int j = 0; j < NPROP; ++j) sel[j] = j;  // argsort(zeros) stable = identity
        }
    }
    __syncthreads();
    if (tid < NPROP) {
        int sidx = sel[tid];
        out[3*tid+0] = world[3*sidx+0];
        out[3*tid+1] = world[3*sidx+1];
        out[3*tid+2] = world[3*sidx+2];
        out[3*NPROP + tid] = 0.0f;                 // probs
        out[4*NPROP + 3*tid + 0] = scv[3*sidx+0];
        out[4*NPROP + 3*tid + 1] = scv[3*sidx+1];
        out[4*NPROP + 3*tid + 2] = scv[3*sidx+2];
    }
}

extern "C" void kernel_launch(void* const* d_in, const int* in_sizes, int n_in,
                              void* d_out, int out_size, void* d_ws, size_t ws_size,
                              hipStream_t stream) {
    const float* pc      = (const float*)d_in[0];
    const float* xyz     = (const float*)d_in[1];
    const float* scale   = (const float*)d_in[2];
    const float* prob    = (const float*)d_in[3];
    const float* corners = (const float*)d_in[4];
    const float* vp      = (const float*)d_in[5];
    int N = in_sizes[0] / 3;
    int M = in_sizes[5] / 3;

    const size_t G = (size_t)GXD * GYD * GZD;  // 8,286,208
    float* gobj    = (float*)d_ws;
    float* sumdist = gobj + G;          // 1 float, covered by the memset below
    float* logits  = sumdist + 1;
    float* u_th    = logits + CCLS;
    int*   yidx    = (int*)(u_th + CCLS);
    int*   samples = yidx + CCLS;
    int*   hkeys   = samples + KSMP;
    float* gsmall  = (float*)(hkeys + HSLOTS);
    float* world   = gsmall + 3*HSLOTS;
    float* scv     = world + 3*KSMP;
    int*   keep    = (int*)(scv + 3*KSMP);
    size_t need = (size_t)((char*)(keep + KSMP) - (char*)d_ws);
    if (ws_size < need) {
        fprintf(stderr, "kernel_launch: ws_size %zu < needed %zu\n", ws_size, need);
        return;
    }

    // zero grid_obj + sumdist (hkeys/gsmall are initialized by k_build_table)
    hipMemsetAsync(gobj, 0, (G + 1)*sizeof(float), stream);

    // rotation table: f32 theta chain exactly as reference, cos/sin in double -> f32
    RotTab rt;
    const float twopi = (float)(2.0 * M_PI);
    for (int r = 0; r < NROT; ++r) {
        float th = (twopi * (float)r) / 36.0f;
        rt.c[r] = (float)cos((double)th);
        rt.s[r] = (float)sin((double)th);
    }

    dim3 sgrid((N + 255) / 256, NROT);
    k_scatter<<<sgrid, 256, 0, stream>>>(pc, xyz, prob, corners, gobj, N, rt);
    k_colmax<<<(CCLS + 255) / 256, 256, 0, stream>>>(gobj, logits, yidx, sumdist);
    k_thresh<<<(CCLS + 255) / 256, 256, 0, stream>>>(logits, sumdist, u_th);
    k_sample<<<KSMP, 256, 0, stream>>>(logits, u_th, samples);
    k_build_table<<<1, 256, 0, stream>>>(samples, yidx, hkeys, gsmall);
    k_scale_scatter<<<sgrid, 256, 0, stream>>>(pc, xyz, scale, prob, corners, hkeys, gsmall, N, rt);
    k_post<<<(KSMP + 255) / 256, 256, 0, stream>>>(gobj, hkeys, gsmall, yidx, samples, corners, vp, M, world, scv, keep);
    k_select<<<1, 256, 0, stream>>>(world, scv, keep, (float*)d_out);
}

// Round 5
// 552.295 us; speedup vs baseline: 2.8302x; 1.2611x over previous
//
#include <hip/hip_runtime.h>
#include <math.h>
#include <stdio.h>
#include <stdint.h>

#define GXD 272
#define GYD 112
#define GZD 272
#define NROT 36
#define CCLS (GXD*GZD)     /* 73984 */
#define HCOLS (CCLS/2)     /* 36992 */
#define KSMP 1024          /* NUM_PROPOSAL*OVERSAMPLE */
#define NPROP 256
#define HSLOTS 2048        /* sampled-cell hash table slots */
#define SCAP 1024          /* survivor capacity per sample-block */

struct RotTab { float c[NROT]; float s[NROT]; };

__device__ __forceinline__ uint32_t cell_hash(int flat) {
    return ((uint32_t)flat * 2654435761u) >> 21;  // top 11 bits -> 0..2047
}

// ---------------- threefry2x32 (JAX semantics, 20 rounds) ----------------
__device__ __forceinline__ void threefry2x32(uint32_t k0, uint32_t k1,
                                             uint32_t x0, uint32_t x1,
                                             uint32_t& o0, uint32_t& o1) {
    uint32_t ks2 = k0 ^ k1 ^ 0x1BD11BDAu;
#define TF_ROUND(r) { x0 += x1; x1 = (x1 << (r)) | (x1 >> (32 - (r))); x1 ^= x0; }
    x0 += k0; x1 += k1;
    TF_ROUND(13) TF_ROUND(15) TF_ROUND(26) TF_ROUND(6)
    x0 += k1;  x1 += ks2 + 1u;
    TF_ROUND(17) TF_ROUND(29) TF_ROUND(16) TF_ROUND(24)
    x0 += ks2; x1 += k0 + 2u;
    TF_ROUND(13) TF_ROUND(15) TF_ROUND(26) TF_ROUND(6)
    x0 += k0;  x1 += k1 + 3u;
    TF_ROUND(17) TF_ROUND(29) TF_ROUND(16) TF_ROUND(24)
    x0 += k1;  x1 += ks2 + 4u;
    TF_ROUND(13) TF_ROUND(15) TF_ROUND(26) TF_ROUND(6)
    x0 += ks2; x1 += k0 + 5u;
#undef TF_ROUND
    o0 = x0; o1 = x1;
}

__device__ __forceinline__ float uniform_from_bits(uint32_t b) {
    const float TINY = 1.1754943508222875e-38f; // np.finfo(float32).tiny
    float f = __uint_as_float((b >> 9) | 0x3f800000u) - 1.0f;
    float u = __fadd_rn(__fmul_rn(f, 1.0f), TINY);
    return fmaxf(TINY, u);
}

// gumbel = -log(-log(u)); f32 logs via double rounding (== correctly-rounded logf)
__device__ __forceinline__ float gumbel_from_u(float u) {
    float l1 = (float)log((double)u);
    float l2 = (float)log((double)(-l1));
    return -l2;
}

// shared vote-cell computation (must stay bit-identical across passes)
__device__ __forceinline__ bool vote_cell(float px, float py, float pz,
                                          float ox, float oy, float oz,
                                          float c, float s,
                                          float c0x, float c0y, float c0z,
                                          int& flat) {
    float ty = __fadd_rn(py, oy);
    float vy = __fadd_rn(__fdiv_rn(__fsub_rn(ty, c0y), 0.03f), 0.5f);
    int iy = (int)floorf(vy);
    if (iy < 0 || iy >= GYD) return false;
    float rx = __fadd_rn(__fmul_rn(ox, c), __fmul_rn(oz, s));
    float rz = __fadd_rn(__fmul_rn(-ox, s), __fmul_rn(oz, c));
    float tx = __fadd_rn(px, rx);
    float tz = __fadd_rn(pz, rz);
    float vx = __fadd_rn(__fdiv_rn(__fsub_rn(tx, c0x), 0.03f), 0.5f);
    float vz = __fadd_rn(__fdiv_rn(__fsub_rn(tz, c0z), 0.03f), 0.5f);
    int ix = (int)floorf(vx);
    int iz = (int)floorf(vz);
    if (ix < 0 || ix >= GXD || iz < 0 || iz >= GZD) return false;
    flat = (ix*GYD + iy)*GZD + iz;
    return true;
}

// ---------------- K1: hough vote scatter, gobj ONLY (1 atomic/vote) ----------------
__global__ __launch_bounds__(256) void k_scatter(const float* __restrict__ pc, const float* __restrict__ xyz,
                          const float* __restrict__ prob, const float* __restrict__ corners,
                          float* __restrict__ gobj, int N, RotTab rt) {
    int i = blockIdx.x * blockDim.x + threadIdx.x;
    int r = blockIdx.y;
    if (i >= N) return;
    int flat;
    if (!vote_cell(pc[3*i], pc[3*i+1], pc[3*i+2], xyz[3*i], xyz[3*i+1], xyz[3*i+2],
                   rt.c[r], rt.s[r], corners[0], corners[1], corners[2], flat)) return;
    atomicAdd(&gobj[flat], prob[i]);
}

// ---------------- K2: per-(x,z) max/argmax over y; logits; sum(dist) ----------------
__global__ __launch_bounds__(256) void k_colmax(const float* __restrict__ gobj,
                         float* __restrict__ logits, int* __restrict__ yidx,
                         float* __restrict__ sumdist) {
    int c = blockIdx.x * blockDim.x + threadIdx.x;
    float d = 0.0f;
    if (c < CCLS) {
        int x = c / GZD, z = c % GZD;
        const float* base = gobj + (size_t)x*GYD*GZD + z;
        float m = base[0];
        int mi = 0;
        for (int y = 1; y < GYD; ++y) {
            float v = base[(size_t)y*GZD];
            if (v > m) { m = v; mi = y; }  // strict > => first occurrence
        }
        d = __fsqrt_rn(__fadd_rn(m, 1e-7f));
        yidx[c] = mi;
        logits[c] = (float)log((double)__fadd_rn(d, 1e-30f));
    }
    __shared__ float sred[256];
    int tid = threadIdx.x;
    sred[tid] = d; __syncthreads();
    for (int off = 128; off > 0; off >>= 1) {
        if (tid < off) sred[tid] += sred[tid+off];
        __syncthreads();
    }
    if (tid == 0) atomicAdd(sumdist, sred[0]);
}

// ---------------- K2b: per-column integer bits-threshold ----------------
// survivor v = gumbel(u)+L > B0  <=>  u > u* = exp(-exp(L-B0)).  u = (bits>>9)*2^-23
// (monotone in bits).  Store bth = (floor(u*·2^23)-2)<<9: test (bits >= bth) can
// only OVER-include vs the exact condition (margin 2 mantissa steps + 0.05 in B0).
__global__ __launch_bounds__(256) void k_thresh(const float* __restrict__ logits,
                                                const float* __restrict__ sumdist,
                                                uint32_t* __restrict__ bth) {
    int c = blockIdx.x * blockDim.x + threadIdx.x;
    if (c >= CCLS) return;
    double B0 = log((double)*sumdist) - 3.0;
    double t = exp(-exp((double)logits[c] - (B0 - 0.05)));
    long long k_th = (long long)floor(t * 8388608.0) - 2;
    uint32_t b;
    if (k_th <= 0)              b = 0u;           // everything survives
    else if (k_th >= 8388608LL) b = 0xFFFFFFFFu;  // ~nothing survives (bits==~0 over-includes, harmless)
    else                        b = (uint32_t)k_th << 9;
    bth[c] = b;
}

// ---------------- K3: categorical sampling — integer prefilter + exact eval ----------------
// grid (2, KSMP): blockIdx.y = row k, blockIdx.x = column half. Hot loop is
// threefry + uint compare only; survivors (few) get the exact f32 gumbel chain.
__global__ __launch_bounds__(256) void k_sample(const float* __restrict__ logits,
                                                const uint32_t* __restrict__ bth,
                                                float* __restrict__ pval,
                                                int* __restrict__ pidx) {
    int half = blockIdx.x;
    int k = blockIdx.y;
    int tid = threadIdx.x;
    int cstart = half * HCOLS;
    uint32_t base = (uint32_t)k * (uint32_t)CCLS + (uint32_t)cstart;

    __shared__ int cnt;
    __shared__ int      svc[SCAP];
    __shared__ uint32_t svb[SCAP];
    __shared__ float sv[256];
    __shared__ int   si[256];
    if (tid == 0) cnt = 0;
    __syncthreads();

    for (int j = tid; j < HCOLS; j += 256) {
        uint32_t o0, o1;
        threefry2x32(0u, 42u, 0u, base + (uint32_t)j, o0, o1);
        uint32_t bits = o0 ^ o1;
        if (bits >= bth[cstart + j]) {       // rare
            int idx = atomicAdd(&cnt, 1);
            if (idx < SCAP) { svc[idx] = cstart + j; svb[idx] = bits; }
        }
    }
    __syncthreads();

    int n = cnt;
    float best = -INFINITY; int bc = 0x7fffffff;
    if (n > 0 && n <= SCAP) {
        for (int j = tid; j < n; j += 256) {
            int c = svc[j];
            float v = __fadd_rn(gumbel_from_u(uniform_from_bits(svb[j])), logits[c]);
            if (v > best || (v == best && c < bc)) { best = v; bc = c; }
        }
    } else {
        // empty (all v <= B0-cut in range) or overflow: exact full scan of range
        for (int j = tid; j < HCOLS; j += 256) {
            int c = cstart + j;
            uint32_t o0, o1;
            threefry2x32(0u, 42u, 0u, base + (uint32_t)j, o0, o1);
            float v = __fadd_rn(gumbel_from_u(uniform_from_bits(o0 ^ o1)), logits[c]);
            if (v > best || (v == best && c < bc)) { best = v; bc = c; }
        }
    }
    sv[tid] = best; si[tid] = bc; __syncthreads();
    for (int off = 128; off > 0; off >>= 1) {
        if (tid < off) {
            float v2 = sv[tid+off]; int i2 = si[tid+off];
            if (v2 > sv[tid] || (v2 == sv[tid] && i2 < si[tid])) { sv[tid] = v2; si[tid] = i2; }
        }
        __syncthreads();
    }
    if (tid == 0) { pval[2*k + half] = sv[0]; pidx[2*k + half] = si[0]; }
}

// ---------------- K3m: merge halves ----------------
__global__ void k_merge(const float* __restrict__ pval, const int* __restrict__ pidx,
                        int* __restrict__ samples) {
    int k = blockIdx.x * blockDim.x + threadIdx.x;
    if (k >= KSMP) return;
    float v0 = pval[2*k], v1 = pval[2*k+1];
    // half0 columns are all lower-indexed than half1's -> ties go to half0
    samples[k] = (v1 > v0) ? pidx[2*k+1] : pidx[2*k];
}

// ---------------- K3b: build sampled-cell hash table (single block) ----------------
__global__ __launch_bounds__(256) void k_build_table(const int* __restrict__ samples,
                                                     const int* __restrict__ yidx,
                                                     int* __restrict__ hkeys,
                                                     float* __restrict__ gsmall) {
    int tid = threadIdx.x;
    for (int j = tid; j < HSLOTS; j += 256) hkeys[j] = -1;
    for (int j = tid; j < 3*HSLOTS; j += 256) gsmall[j] = 0.0f;
    __syncthreads();
    for (int k = tid; k < KSMP; k += 256) {
        int s = samples[k];
        int xi = s / GZD, zi = s % GZD;
        int yi = yidx[s];
        int flat = (xi*GYD + yi)*GZD + zi;
        uint32_t h = cell_hash(flat);
        for (;;) {
            int prev = atomicCAS(&hkeys[h], -1, flat);
            if (prev == -1 || prev == flat) break;
            h = (h + 1) & (HSLOTS - 1);
        }
    }
}

// ---------------- K3c: replay votes, accumulate scale sums at sampled cells ----------------
__global__ __launch_bounds__(256) void k_scale_scatter(const float* __restrict__ pc, const float* __restrict__ xyz,
                          const float* __restrict__ scale, const float* __restrict__ prob,
                          const float* __restrict__ corners,
                          const int* __restrict__ hkeys, float* __restrict__ gsmall,
                          int N, RotTab rt) {
    __shared__ int lk[HSLOTS];
    for (int j = threadIdx.x; j < HSLOTS; j += 256) lk[j] = hkeys[j];
    __syncthreads();
    int i = blockIdx.x * blockDim.x + threadIdx.x;
    int r = blockIdx.y;
    if (i >= N) return;
    int flat;
    if (!vote_cell(pc[3*i], pc[3*i+1], pc[3*i+2], xyz[3*i], xyz[3*i+1], xyz[3*i+2],
                   rt.c[r], rt.s[r], corners[0], corners[1], corners[2], flat)) return;
    uint32_t h = cell_hash(flat);
    int slot = -1;
    for (;;) {
        int key = lk[h];
        if (key == flat) { slot = (int)h; break; }
        if (key == -1) break;
        h = (h + 1) & (HSLOTS - 1);
    }
    if (slot < 0) return;
    float w0 = prob[i];
    atomicAdd(&gsmall[3*slot+0], __fmul_rn(w0, scale[3*i]));
    atomicAdd(&gsmall[3*slot+1], __fmul_rn(w0, scale[3*i+1]));
    atomicAdd(&gsmall[3*slot+2], __fmul_rn(w0, scale[3*i+2]));
}

// ---------------- K4: one block per sample — world loc, scale, keep ----------------
__global__ __launch_bounds__(256) void k_post(const float* __restrict__ gobj,
                       const int* __restrict__ hkeys, const float* __restrict__ gsmall,
                       const int* __restrict__ yidx, const int* __restrict__ samples,
                       const float* __restrict__ corners, const float* __restrict__ vp, int M,
                       float* __restrict__ world, float* __restrict__ scv, int* __restrict__ keep) {
    int k = blockIdx.x;
    int tid = threadIdx.x;
    int s = samples[k];
    int xi = s / GZD, zi = s % GZD;
    int yi = yidx[s];
    float wx = __fadd_rn(__fmul_rn((float)xi, 0.03f), corners[0]);
    float wy = __fadd_rn(__fmul_rn((float)yi, 0.03f), corners[1]);
    float wz = __fadd_rn(__fmul_rn((float)zi, 0.03f), corners[2]);

    float dmin = INFINITY;
    for (int j = tid; j < M; j += 256) {
        float dx = __fsub_rn(wx, vp[3*j]);
        float dy = __fsub_rn(wy, vp[3*j+1]);
        float dz = __fsub_rn(wz, vp[3*j+2]);
        float sq = __fadd_rn(__fadd_rn(__fmul_rn(dx,dx), __fmul_rn(dy,dy)), __fmul_rn(dz,dz));
        dmin = fminf(dmin, __fsqrt_rn(sq));
    }
    __shared__ float sm[256];
    sm[tid] = dmin; __syncthreads();
    for (int off = 128; off > 0; off >>= 1) {
        if (tid < off) sm[tid] = fminf(sm[tid], sm[tid+off]);
        __syncthreads();
    }
    if (tid == 0) {
        world[3*k] = wx; world[3*k+1] = wy; world[3*k+2] = wz;
        int flat = (xi*GYD + yi)*GZD + zi;
        uint32_t h = cell_hash(flat);
        while (hkeys[h] != flat) h = (h + 1) & (HSLOTS - 1);  // guaranteed present
        float go = __fadd_rn(gobj[flat], 1e-7f);
        scv[3*k+0] = __fdiv_rn(gsmall[3*h+0], go);
        scv[3*k+1] = __fdiv_rn(gsmall[3*h+1], go);
        scv[3*k+2] = __fdiv_rn(gsmall[3*h+2], go);
        keep[k] = (sm[0] < 0.3f) ? 1 : 0;
    }
}

// ---------------- K5: stable 0/1 selection + output write ----------------
__global__ __launch_bounds__(256) void k_select(const float* __restrict__ world,
                                                const float* __restrict__ scv,
                                                const int* __restrict__ keep,
                                                float* __restrict__ out) {
    __shared__ int kp[KSMP];
    __shared__ int sel[NPROP];
    int tid = threadIdx.x;
    for (int j = tid; j < KSMP; j += 256) kp[j] = keep[j];
    __syncthreads();
    if (tid == 0) {
        int any = 0;
        for (int j = 0; j < KSMP; ++j) any |= kp[j];
        int cnt = 0;
        if (any) {
            for (int j = 0; j < KSMP && cnt < NPROP; ++j) if (kp[j])  sel[cnt++] = j;
            for (int j = 0; j < KSMP && cnt < NPROP; ++j) if (!kp[j]) sel[cnt++] = j;
        } else {
            for (int j = 0; j < NPROP; ++j) sel[j] = j;  // argsort(zeros) stable = identity
        }
    }
    __syncthreads();
    if (tid < NPROP) {
        int sidx = sel[tid];
        out[3*tid+0] = world[3*sidx+0];
        out[3*tid+1] = world[3*sidx+1];
        out[3*tid+2] = world[3*sidx+2];
        out[3*NPROP + tid] = 0.0f;                 // probs
        out[4*NPROP + 3*tid + 0] = scv[3*sidx+0];
        out[4*NPROP + 3*tid + 1] = scv[3*sidx+1];
        out[4*NPROP + 3*tid + 2] = scv[3*sidx+2];
    }
}

extern "C" void kernel_launch(void* const* d_in, const int* in_sizes, int n_in,
                              void* d_out, int out_size, void* d_ws, size_t ws_size,
                              hipStream_t stream) {
    const float* pc      = (const float*)d_in[0];
    const float* xyz     = (const float*)d_in[1];
    const float* scale   = (const float*)d_in[2];
    const float* prob    = (const float*)d_in[3];
    const float* corners = (const float*)d_in[4];
    const float* vp      = (const float*)d_in[5];
    int N = in_sizes[0] / 3;
    int M = in_sizes[5] / 3;

    const size_t G = (size_t)GXD * GYD * GZD;  // 8,286,208
    float* gobj    = (float*)d_ws;
    float* sumdist = gobj + G;          // 1 float, covered by the memset below
    float* logits  = sumdist + 1;
    uint32_t* bth  = (uint32_t*)(logits + CCLS);
    int*   yidx    = (int*)(bth + CCLS);
    float* pval    = (float*)(yidx + CCLS);
    int*   pidx    = (int*)(pval + 2*KSMP);
    int*   samples = pidx + 2*KSMP;
    int*   hkeys   = samples + KSMP;
    float* gsmall  = (float*)(hkeys + HSLOTS);
    float* world   = gsmall + 3*HSLOTS;
    float* scv     = world + 3*KSMP;
    int*   keep    = (int*)(scv + 3*KSMP);
    size_t need = (size_t)((char*)(keep + KSMP) - (char*)d_ws);
    if (ws_size < need) {
        fprintf(stderr, "kernel_launch: ws_size %zu < needed %zu\n", ws_size, need);
        return;
    }

    // zero grid_obj + sumdist
    hipMemsetAsync(gobj, 0, (G + 1)*sizeof(float), stream);

    // rotation table: f32 theta chain exactly as reference, cos/sin in double -> f32
    RotTab rt;
    const float twopi = (float)(2.0 * M_PI);
    for (int r = 0; r < NROT; ++r) {
        float th = (twopi * (float)r) / 36.0f;
        rt.c[r] = (float)cos((double)th);
        rt.s[r] = (float)sin((double)th);
    }

    dim3 sgrid((N + 255) / 256, NROT);
    k_scatter<<<sgrid, 256, 0, stream>>>(pc, xyz, prob, corners, gobj, N, rt);
    k_colmax<<<(CCLS + 255) / 256, 256, 0, stream>>>(gobj, logits, yidx, sumdist);
    k_thresh<<<(CCLS + 255) / 256, 256, 0, stream>>>(logits, sumdist, bth);
    dim3 samp_grid(2, KSMP);
    k_sample<<<samp_grid, 256, 0, stream>>>(logits, bth, pval, pidx);
    k_merge<<<(KSMP + 255) / 256, 256, 0, stream>>>(pval, pidx, samples);
    k_build_table<<<1, 256, 0, stream>>>(samples, yidx, hkeys, gsmall);
    k_scale_scatter<<<sgrid, 256, 0, stream>>>(pc, xyz, scale, prob, corners, hkeys, gsmall, N, rt);
    k_post<<<KSMP, 256, 0, stream>>>(gobj, hkeys, gsmall, yidx, samples, corners, vp, M, world, scv, keep);
    k_select<<<1, 256, 0, stream>>>(world, scv, keep, (float*)d_out);
}

// Round 6
// 540.274 us; speedup vs baseline: 2.8932x; 1.0222x over previous
//
#include <hip/hip_runtime.h>
#include <math.h>
#include <stdio.h>
#include <stdint.h>

#define GXD 272
#define GYD 112
#define GZD 272
#define NROT 36
#define CCLS (GXD*GZD)     /* 73984 */
#define HCOLS (CCLS/2)     /* 36992, divisible by 4 */
#define KSMP 1024          /* NUM_PROPOSAL*OVERSAMPLE */
#define NPROP 256
#define HSLOTS 2048        /* sampled-cell hash table slots */
#define SCAP 1024          /* survivor capacity per sample-block */

struct RotTab { float c[NROT]; float s[NROT]; };

__device__ __forceinline__ uint32_t cell_hash(int flat) {
    return ((uint32_t)flat * 2654435761u) >> 21;  // top 11 bits -> 0..2047
}

// rotl via single v_alignbit_b32: alignbit(x,x,s) = rotr(x,s); rotl(x,r)=rotr(x,32-r)
#define ROTL_AB(x, r) __builtin_amdgcn_alignbit((x), (x), 32u - (r))

// ---------------- threefry2x32 (JAX semantics, 20 rounds) ----------------
__device__ __forceinline__ void threefry2x32(uint32_t k0, uint32_t k1,
                                             uint32_t x0, uint32_t x1,
                                             uint32_t& o0, uint32_t& o1) {
    uint32_t ks2 = k0 ^ k1 ^ 0x1BD11BDAu;
#define TF_ROUND(r) { x0 += x1; x1 = ROTL_AB(x1, r); x1 ^= x0; }
    x0 += k0; x1 += k1;
    TF_ROUND(13) TF_ROUND(15) TF_ROUND(26) TF_ROUND(6)
    x0 += k1;  x1 += ks2 + 1u;
    TF_ROUND(17) TF_ROUND(29) TF_ROUND(16) TF_ROUND(24)
    x0 += ks2; x1 += k0 + 2u;
    TF_ROUND(13) TF_ROUND(15) TF_ROUND(26) TF_ROUND(6)
    x0 += k0;  x1 += k1 + 3u;
    TF_ROUND(17) TF_ROUND(29) TF_ROUND(16) TF_ROUND(24)
    x0 += k1;  x1 += ks2 + 4u;
    TF_ROUND(13) TF_ROUND(15) TF_ROUND(26) TF_ROUND(6)
    x0 += ks2; x1 += k0 + 5u;
#undef TF_ROUND
    o0 = x0; o1 = x1;
}

// specialized: key (0,42), counter (0, i) -> o0^o1 (partitionable random_bits)
__device__ __forceinline__ uint32_t tf_bits(uint32_t i) {
    uint32_t o0, o1;
    threefry2x32(0u, 42u, 0u, i, o0, o1);
    return o0 ^ o1;
}

__device__ __forceinline__ float uniform_from_bits(uint32_t b) {
    const float TINY = 1.1754943508222875e-38f; // np.finfo(float32).tiny
    float f = __uint_as_float((b >> 9) | 0x3f800000u) - 1.0f;
    float u = __fadd_rn(__fmul_rn(f, 1.0f), TINY);
    return fmaxf(TINY, u);
}

// gumbel = -log(-log(u)); f32 logs via double rounding (== correctly-rounded logf)
__device__ __forceinline__ float gumbel_from_u(float u) {
    float l1 = (float)log((double)u);
    float l2 = (float)log((double)(-l1));
    return -l2;
}

// shared vote-cell computation (must stay bit-identical across passes)
__device__ __forceinline__ bool vote_cell(float px, float py, float pz,
                                          float ox, float oy, float oz,
                                          float c, float s,
                                          float c0x, float c0y, float c0z,
                                          int& flat) {
    float ty = __fadd_rn(py, oy);
    float vy = __fadd_rn(__fdiv_rn(__fsub_rn(ty, c0y), 0.03f), 0.5f);
    int iy = (int)floorf(vy);
    if (iy < 0 || iy >= GYD) return false;
    float rx = __fadd_rn(__fmul_rn(ox, c), __fmul_rn(oz, s));
    float rz = __fadd_rn(__fmul_rn(-ox, s), __fmul_rn(oz, c));
    float tx = __fadd_rn(px, rx);
    float tz = __fadd_rn(pz, rz);
    float vx = __fadd_rn(__fdiv_rn(__fsub_rn(tx, c0x), 0.03f), 0.5f);
    float vz = __fadd_rn(__fdiv_rn(__fsub_rn(tz, c0z), 0.03f), 0.5f);
    int ix = (int)floorf(vx);
    int iz = (int)floorf(vz);
    if (ix < 0 || ix >= GXD || iz < 0 || iz >= GZD) return false;
    flat = (ix*GYD + iy)*GZD + iz;
    return true;
}

// ---------------- K1: hough vote scatter, gobj ONLY (1 atomic/vote) ----------------
__global__ __launch_bounds__(256) void k_scatter(const float* __restrict__ pc, const float* __restrict__ xyz,
                          const float* __restrict__ prob, const float* __restrict__ corners,
                          float* __restrict__ gobj, int N, RotTab rt) {
    int i = blockIdx.x * blockDim.x + threadIdx.x;
    int r = blockIdx.y;
    if (i >= N) return;
    int flat;
    if (!vote_cell(pc[3*i], pc[3*i+1], pc[3*i+2], xyz[3*i], xyz[3*i+1], xyz[3*i+2],
                   rt.c[r], rt.s[r], corners[0], corners[1], corners[2], flat)) return;
    atomicAdd(&gobj[flat], prob[i]);
}

// ---------------- K2: per-(x,z) max/argmax over y; logits; sum(dist) ----------------
__global__ __launch_bounds__(256) void k_colmax(const float* __restrict__ gobj,
                         float* __restrict__ logits, int* __restrict__ yidx,
                         float* __restrict__ sumdist) {
    int c = blockIdx.x * blockDim.x + threadIdx.x;
    float d = 0.0f;
    if (c < CCLS) {
        int x = c / GZD, z = c % GZD;
        const float* base = gobj + (size_t)x*GYD*GZD + z;
        float m = base[0];
        int mi = 0;
        for (int y = 1; y < GYD; ++y) {
            float v = base[(size_t)y*GZD];
            if (v > m) { m = v; mi = y; }  // strict > => first occurrence
        }
        d = __fsqrt_rn(__fadd_rn(m, 1e-7f));
        yidx[c] = mi;
        logits[c] = (float)log((double)__fadd_rn(d, 1e-30f));
    }
    __shared__ float sred[256];
    int tid = threadIdx.x;
    sred[tid] = d; __syncthreads();
    for (int off = 128; off > 0; off >>= 1) {
        if (tid < off) sred[tid] += sred[tid+off];
        __syncthreads();
    }
    if (tid == 0) atomicAdd(sumdist, sred[0]);
}

// ---------------- K2b: per-column integer bits-threshold ----------------
// survivor v = gumbel(u)+L > B0  <=>  u > u* = exp(-exp(L-B0)).  u = (bits>>9)*2^-23
// (monotone in bits).  Store bth = (floor(u*·2^23)-2)<<9: test (bits >= bth) can
// only OVER-include vs the exact condition (margin 2 mantissa steps + 0.05 in B0).
__global__ __launch_bounds__(256) void k_thresh(const float* __restrict__ logits,
                                                const float* __restrict__ sumdist,
                                                uint32_t* __restrict__ bth) {
    int c = blockIdx.x * blockDim.x + threadIdx.x;
    if (c >= CCLS) return;
    double B0 = log((double)*sumdist) - 3.0;
    double t = exp(-exp((double)logits[c] - (B0 - 0.05)));
    long long k_th = (long long)floor(t * 8388608.0) - 2;
    uint32_t b;
    if (k_th <= 0)              b = 0u;           // everything survives
    else if (k_th >= 8388608LL) b = 0xFFFFFFFFu;  // ~nothing survives (bits==~0 over-includes, harmless)
    else                        b = (uint32_t)k_th << 9;
    bth[c] = b;
}

// ---------------- K3: categorical sampling — integer prefilter + exact eval ----------------
// grid (2, KSMP): blockIdx.y = row k, blockIdx.x = column half. Hot loop:
// 4 threefry/thread-iter (alignbit rotates) + one uint4 bth load + 1 branch.
__global__ __launch_bounds__(256) void k_sample(const float* __restrict__ logits,
                                                const uint32_t* __restrict__ bth,
                                                float* __restrict__ pval,
                                                int* __restrict__ pidx) {
    int half = blockIdx.x;
    int k = blockIdx.y;
    int tid = threadIdx.x;
    int cstart = half * HCOLS;
    uint32_t base = (uint32_t)k * (uint32_t)CCLS + (uint32_t)cstart;

    __shared__ int cnt;
    __shared__ int      svc[SCAP];
    __shared__ uint32_t svb[SCAP];
    __shared__ float sv[256];
    __shared__ int   si[256];
    if (tid == 0) cnt = 0;
    __syncthreads();

    const uint4* bt4 = (const uint4*)(bth + cstart);
    for (int q = tid; q < HCOLS/4; q += 256) {
        int j0 = q * 4;
        uint4 bt = bt4[q];
        uint32_t b0 = tf_bits(base + (uint32_t)j0);
        uint32_t b1 = tf_bits(base + (uint32_t)j0 + 1u);
        uint32_t b2 = tf_bits(base + (uint32_t)j0 + 2u);
        uint32_t b3 = tf_bits(base + (uint32_t)j0 + 3u);
        bool h0 = b0 >= bt.x, h1 = b1 >= bt.y, h2 = b2 >= bt.z, h3 = b3 >= bt.w;
        if (__builtin_expect(h0 | h1 | h2 | h3, 0)) {
            if (h0) { int idx = atomicAdd(&cnt, 1); if (idx < SCAP) { svc[idx] = cstart + j0;     svb[idx] = b0; } }
            if (h1) { int idx = atomicAdd(&cnt, 1); if (idx < SCAP) { svc[idx] = cstart + j0 + 1; svb[idx] = b1; } }
            if (h2) { int idx = atomicAdd(&cnt, 1); if (idx < SCAP) { svc[idx] = cstart + j0 + 2; svb[idx] = b2; } }
            if (h3) { int idx = atomicAdd(&cnt, 1); if (idx < SCAP) { svc[idx] = cstart + j0 + 3; svb[idx] = b3; } }
        }
    }
    __syncthreads();

    int n = cnt;
    float best = -INFINITY; int bc = 0x7fffffff;
    if (n > 0 && n <= SCAP) {
        for (int j = tid; j < n; j += 256) {
            int c = svc[j];
            float v = __fadd_rn(gumbel_from_u(uniform_from_bits(svb[j])), logits[c]);
            if (v > best || (v == best && c < bc)) { best = v; bc = c; }
        }
    } else {
        // empty (all v <= B0-cut in range) or overflow: exact full scan of range
        for (int j = tid; j < HCOLS; j += 256) {
            int c = cstart + j;
            float v = __fadd_rn(gumbel_from_u(uniform_from_bits(tf_bits(base + (uint32_t)j))), logits[c]);
            if (v > best || (v == best && c < bc)) { best = v; bc = c; }
        }
    }
    sv[tid] = best; si[tid] = bc; __syncthreads();
    for (int off = 128; off > 0; off >>= 1) {
        if (tid < off) {
            float v2 = sv[tid+off]; int i2 = si[tid+off];
            if (v2 > sv[tid] || (v2 == sv[tid] && i2 < si[tid])) { sv[tid] = v2; si[tid] = i2; }
        }
        __syncthreads();
    }
    if (tid == 0) { pval[2*k + half] = sv[0]; pidx[2*k + half] = si[0]; }
}

// ---------------- K3m: merge halves ----------------
__global__ void k_merge(const float* __restrict__ pval, const int* __restrict__ pidx,
                        int* __restrict__ samples) {
    int k = blockIdx.x * blockDim.x + threadIdx.x;
    if (k >= KSMP) return;
    float v0 = pval[2*k], v1 = pval[2*k+1];
    // half0 columns are all lower-indexed than half1's -> ties go to half0
    samples[k] = (v1 > v0) ? pidx[2*k+1] : pidx[2*k];
}

// ---------------- K3b: build sampled-cell hash table (single block) ----------------
__global__ __launch_bounds__(256) void k_build_table(const int* __restrict__ samples,
                                                     const int* __restrict__ yidx,
                                                     int* __restrict__ hkeys,
                                                     float* __restrict__ gsmall) {
    int tid = threadIdx.x;
    for (int j = tid; j < HSLOTS; j += 256) hkeys[j] = -1;
    for (int j = tid; j < 3*HSLOTS; j += 256) gsmall[j] = 0.0f;
    __syncthreads();
    for (int k = tid; k < KSMP; k += 256) {
        int s = samples[k];
        int xi = s / GZD, zi = s % GZD;
        int yi = yidx[s];
        int flat = (xi*GYD + yi)*GZD + zi;
        uint32_t h = cell_hash(flat);
        for (;;) {
            int prev = atomicCAS(&hkeys[h], -1, flat);
            if (prev == -1 || prev == flat) break;
            h = (h + 1) & (HSLOTS - 1);
        }
    }
}

// ---------------- K3c: replay votes, accumulate scale sums at sampled cells ----------------
__global__ __launch_bounds__(256) void k_scale_scatter(const float* __restrict__ pc, const float* __restrict__ xyz,
                          const float* __restrict__ scale, const float* __restrict__ prob,
                          const float* __restrict__ corners,
                          const int* __restrict__ hkeys, float* __restrict__ gsmall,
                          int N, RotTab rt) {
    __shared__ int lk[HSLOTS];
    for (int j = threadIdx.x; j < HSLOTS; j += 256) lk[j] = hkeys[j];
    __syncthreads();
    int i = blockIdx.x * blockDim.x + threadIdx.x;
    int r = blockIdx.y;
    if (i >= N) return;
    int flat;
    if (!vote_cell(pc[3*i], pc[3*i+1], pc[3*i+2], xyz[3*i], xyz[3*i+1], xyz[3*i+2],
                   rt.c[r], rt.s[r], corners[0], corners[1], corners[2], flat)) return;
    uint32_t h = cell_hash(flat);
    int slot = -1;
    for (;;) {
        int key = lk[h];
        if (key == flat) { slot = (int)h; break; }
        if (key == -1) break;
        h = (h + 1) & (HSLOTS - 1);
    }
    if (slot < 0) return;
    float w0 = prob[i];
    atomicAdd(&gsmall[3*slot+0], __fmul_rn(w0, scale[3*i]));
    atomicAdd(&gsmall[3*slot+1], __fmul_rn(w0, scale[3*i+1]));
    atomicAdd(&gsmall[3*slot+2], __fmul_rn(w0, scale[3*i+2]));
}

// ---------------- K4: one block per sample — world loc, scale, keep ----------------
__global__ __launch_bounds__(256) void k_post(const float* __restrict__ gobj,
                       const int* __restrict__ hkeys, const float* __restrict__ gsmall,
                       const int* __restrict__ yidx, const int* __restrict__ samples,
                       const float* __restrict__ corners, const float* __restrict__ vp, int M,
                       float* __restrict__ world, float* __restrict__ scv, int* __restrict__ keep) {
    int k = blockIdx.x;
    int tid = threadIdx.x;
    int s = samples[k];
    int xi = s / GZD, zi = s % GZD;
    int yi = yidx[s];
    float wx = __fadd_rn(__fmul_rn((float)xi, 0.03f), corners[0]);
    float wy = __fadd_rn(__fmul_rn((float)yi, 0.03f), corners[1]);
    float wz = __fadd_rn(__fmul_rn((float)zi, 0.03f), corners[2]);

    float dmin = INFINITY;
    for (int j = tid; j < M; j += 256) {
        float dx = __fsub_rn(wx, vp[3*j]);
        float dy = __fsub_rn(wy, vp[3*j+1]);
        float dz = __fsub_rn(wz, vp[3*j+2]);
        float sq = __fadd_rn(__fadd_rn(__fmul_rn(dx,dx), __fmul_rn(dy,dy)), __fmul_rn(dz,dz));
        dmin = fminf(dmin, __fsqrt_rn(sq));
    }
    __shared__ float sm[256];
    sm[tid] = dmin; __syncthreads();
    for (int off = 128; off > 0; off >>= 1) {
        if (tid < off) sm[tid] = fminf(sm[tid], sm[tid+off]);
        __syncthreads();
    }
    if (tid == 0) {
        world[3*k] = wx; world[3*k+1] = wy; world[3*k+2] = wz;
        int flat = (xi*GYD + yi)*GZD + zi;
        uint32_t h = cell_hash(flat);
        while (hkeys[h] != flat) h = (h + 1) & (HSLOTS - 1);  // guaranteed present
        float go = __fadd_rn(gobj[flat], 1e-7f);
        scv[3*k+0] = __fdiv_rn(gsmall[3*h+0], go);
        scv[3*k+1] = __fdiv_rn(gsmall[3*h+1], go);
        scv[3*k+2] = __fdiv_rn(gsmall[3*h+2], go);
        keep[k] = (sm[0] < 0.3f) ? 1 : 0;
    }
}

// ---------------- K5: stable 0/1 selection + output write ----------------
__global__ __launch_bounds__(256) void k_select(const float* __restrict__ world,
                                                const float* __restrict__ scv,
                                                const int* __restrict__ keep,
                                                float* __restrict__ out) {
    __shared__ int kp[KSMP];
    __shared__ int sel[NPROP];
    int tid = threadIdx.x;
    for (int j = tid; j < KSMP; j += 256) kp[j] = keep[j];
    __syncthreads();
    if (tid == 0) {
        int any = 0;
        for (int j = 0; j < KSMP; ++j) any |= kp[j];
        int cnt = 0;
        if (any) {
            for (int j = 0; j < KSMP && cnt < NPROP; ++j) if (kp[j])  sel[cnt++] = j;
            for (int j = 0; j < KSMP && cnt < NPROP; ++j) if (!kp[j]) sel[cnt++] = j;
        } else {
            for (int j = 0; j < NPROP; ++j) sel[j] = j;  // argsort(zeros) stable = identity
        }
    }
    __syncthreads();
    if (tid < NPROP) {
        int sidx = sel[tid];
        out[3*tid+0] = world[3*sidx+0];
        out[3*tid+1] = world[3*sidx+1];
        out[3*tid+2] = world[3*sidx+2];
        out[3*NPROP + tid] = 0.0f;                 // probs
        out[4*NPROP + 3*tid + 0] = scv[3*sidx+0];
        out[4*NPROP + 3*tid + 1] = scv[3*sidx+1];
        out[4*NPROP + 3*tid + 2] = scv[3*sidx+2];
    }
}

extern "C" void kernel_launch(void* const* d_in, const int* in_sizes, int n_in,
                              void* d_out, int out_size, void* d_ws, size_t ws_size,
                              hipStream_t stream) {
    const float* pc      = (const float*)d_in[0];
    const float* xyz     = (const float*)d_in[1];
    const float* scale   = (const float*)d_in[2];
    const float* prob    = (const float*)d_in[3];
    const float* corners = (const float*)d_in[4];
    const float* vp      = (const float*)d_in[5];
    int N = in_sizes[0] / 3;
    int M = in_sizes[5] / 3;

    const size_t G = (size_t)GXD * GYD * GZD;  // 8,286,208
    float* gobj    = (float*)d_ws;
    float* sumdist = gobj + G;          // 1 float, covered by the memset below
    float* logits  = sumdist + 1;
    uint32_t* bth  = (uint32_t*)(logits + CCLS);
    int*   yidx    = (int*)(bth + CCLS);
    float* pval    = (float*)(yidx + CCLS);
    int*   pidx    = (int*)(pval + 2*KSMP);
    int*   samples = pidx + 2*KSMP;
    int*   hkeys   = samples + KSMP;
    float* gsmall  = (float*)(hkeys + HSLOTS);
    float* world   = gsmall + 3*HSLOTS;
    float* scv     = world + 3*KSMP;
    int*   keep    = (int*)(scv + 3*KSMP);
    size_t need = (size_t)((char*)(keep + KSMP) - (char*)d_ws);
    if (ws_size < need) {
        fprintf(stderr, "kernel_launch: ws_size %zu < needed %zu\n", ws_size, need);
        return;
    }

    // zero grid_obj + sumdist
    hipMemsetAsync(gobj, 0, (G + 1)*sizeof(float), stream);

    // rotation table: f32 theta chain exactly as reference, cos/sin in double -> f32
    RotTab rt;
    const float twopi = (float)(2.0 * M_PI);
    for (int r = 0; r < NROT; ++r) {
        float th = (twopi * (float)r) / 36.0f;
        rt.c[r] = (float)cos((double)th);
        rt.s[r] = (float)sin((double)th);
    }

    dim3 sgrid((N + 255) / 256, NROT);
    k_scatter<<<sgrid, 256, 0, stream>>>(pc, xyz, prob, corners, gobj, N, rt);
    k_colmax<<<(CCLS + 255) / 256, 256, 0, stream>>>(gobj, logits, yidx, sumdist);
    k_thresh<<<(CCLS + 255) / 256, 256, 0, stream>>>(logits, sumdist, bth);
    dim3 samp_grid(2, KSMP);
    k_sample<<<samp_grid, 256, 0, stream>>>(logits, bth, pval, pidx);
    k_merge<<<(KSMP + 255) / 256, 256, 0, stream>>>(pval, pidx, samples);
    k_build_table<<<1, 256, 0, stream>>>(samples, yidx, hkeys, gsmall);
    k_scale_scatter<<<sgrid, 256, 0, stream>>>(pc, xyz, scale, prob, corners, hkeys, gsmall, N, rt);
    k_post<<<KSMP, 256, 0, stream>>>(gobj, hkeys, gsmall, yidx, samples, corners, vp, M, world, scv, keep);
    k_select<<<1, 256, 0, stream>>>(world, scv, keep, (float*)d_out);
}

// Round 7
// 476.431 us; speedup vs baseline: 3.2808x; 1.1340x over previous
//
#include <hip/hip_runtime.h>
#include <math.h>
#include <stdio.h>
#include <stdint.h>

#define GXD 272
#define GYD 112
#define GZD 272
#define NROT 36
#define CCLS (GXD*GZD)     /* 73984 */
#define HCOLS (CCLS/2)     /* 36992, divisible by 4 */
#define KSMP 1024          /* NUM_PROPOSAL*OVERSAMPLE */
#define NPROP 256
#define HSLOTS 2048        /* sampled-cell hash table slots */
#define SCAP 1024          /* survivor capacity per sample-block */
#define YH 56              /* y-half size */
#define NBINS (GXD*2)      /* 544: (x-slice, y-half) bins */
#define SLICE (GYD*GZD)    /* 30464 cells per x-slice */

struct RotTab { float c[NROT]; float s[NROT]; };

__device__ __forceinline__ uint32_t cell_hash(int flat) {
    return ((uint32_t)flat * 2654435761u) >> 21;  // top 11 bits -> 0..2047
}

// rotl via single v_alignbit_b32: alignbit(x,x,s) = rotr(x,s); rotl(x,r)=rotr(x,32-r)
#define ROTL_AB(x, r) __builtin_amdgcn_alignbit((x), (x), 32u - (r))

// ---------------- threefry2x32 (JAX semantics, 20 rounds) ----------------
__device__ __forceinline__ void threefry2x32(uint32_t k0, uint32_t k1,
                                             uint32_t x0, uint32_t x1,
                                             uint32_t& o0, uint32_t& o1) {
    uint32_t ks2 = k0 ^ k1 ^ 0x1BD11BDAu;
#define TF_ROUND(r) { x0 += x1; x1 = ROTL_AB(x1, r); x1 ^= x0; }
    x0 += k0; x1 += k1;
    TF_ROUND(13) TF_ROUND(15) TF_ROUND(26) TF_ROUND(6)
    x0 += k1;  x1 += ks2 + 1u;
    TF_ROUND(17) TF_ROUND(29) TF_ROUND(16) TF_ROUND(24)
    x0 += ks2; x1 += k0 + 2u;
    TF_ROUND(13) TF_ROUND(15) TF_ROUND(26) TF_ROUND(6)
    x0 += k0;  x1 += k1 + 3u;
    TF_ROUND(17) TF_ROUND(29) TF_ROUND(16) TF_ROUND(24)
    x0 += k1;  x1 += ks2 + 4u;
    TF_ROUND(13) TF_ROUND(15) TF_ROUND(26) TF_ROUND(6)
    x0 += ks2; x1 += k0 + 5u;
#undef TF_ROUND
    o0 = x0; o1 = x1;
}

// specialized: key (0,42), counter (0, i) -> o0^o1 (partitionable random_bits)
__device__ __forceinline__ uint32_t tf_bits(uint32_t i) {
    uint32_t o0, o1;
    threefry2x32(0u, 42u, 0u, i, o0, o1);
    return o0 ^ o1;
}

__device__ __forceinline__ float uniform_from_bits(uint32_t b) {
    const float TINY = 1.1754943508222875e-38f; // np.finfo(float32).tiny
    float f = __uint_as_float((b >> 9) | 0x3f800000u) - 1.0f;
    float u = __fadd_rn(__fmul_rn(f, 1.0f), TINY);
    return fmaxf(TINY, u);
}

// gumbel = -log(-log(u)); f32 logs via double rounding (== correctly-rounded logf)
__device__ __forceinline__ float gumbel_from_u(float u) {
    float l1 = (float)log((double)u);
    float l2 = (float)log((double)(-l1));
    return -l2;
}

// ---- vote voxel helpers: MUST stay bit-identical across all passes ----
__device__ __forceinline__ bool vote_iy(float py, float oy, float c0y, int& iy) {
    float ty = __fadd_rn(py, oy);
    float vy = __fadd_rn(__fdiv_rn(__fsub_rn(ty, c0y), 0.03f), 0.5f);
    iy = (int)floorf(vy);
    return (iy >= 0 && iy < GYD);
}
__device__ __forceinline__ bool vote_xz(float px, float pz, float ox, float oz,
                                        float c, float s, float c0x, float c0z,
                                        int& ix, int& iz) {
    float rx = __fadd_rn(__fmul_rn(ox, c), __fmul_rn(oz, s));
    float rz = __fadd_rn(__fmul_rn(-ox, s), __fmul_rn(oz, c));
    float tx = __fadd_rn(px, rx);
    float tz = __fadd_rn(pz, rz);
    float vx = __fadd_rn(__fdiv_rn(__fsub_rn(tx, c0x), 0.03f), 0.5f);
    float vz = __fadd_rn(__fdiv_rn(__fsub_rn(tz, c0z), 0.03f), 0.5f);
    ix = (int)floorf(vx);
    iz = (int)floorf(vz);
    return (ix >= 0 && ix < GXD && iz >= 0 && iz < GZD);
}
__device__ __forceinline__ bool vote_cell(float px, float py, float pz,
                                          float ox, float oy, float oz,
                                          float c, float s,
                                          float c0x, float c0y, float c0z,
                                          int& flat) {
    int iy, ix, iz;
    if (!vote_iy(py, oy, c0y, iy)) return false;
    if (!vote_xz(px, pz, ox, oz, c, s, c0x, c0z, ix, iz)) return false;
    flat = (ix*GYD + iy)*GZD + iz;
    return true;
}

// ---------------- K1a: count votes per (x-slice, y-half) bin ----------------
__global__ __launch_bounds__(256) void k_count(const float* __restrict__ pc, const float* __restrict__ xyz,
                          const float* __restrict__ corners, int N, RotTab rt,
                          int* __restrict__ bincnt) {
    __shared__ int h[NBINS];
    int tid = threadIdx.x;
    for (int j = tid; j < NBINS; j += 256) h[j] = 0;
    __syncthreads();
    int i = blockIdx.x * 256 + tid;
    if (i < N) {
        float px = pc[3*i], py = pc[3*i+1], pz = pc[3*i+2];
        float ox = xyz[3*i], oy = xyz[3*i+1], oz = xyz[3*i+2];
        int iy;
        if (vote_iy(py, oy, corners[1], iy)) {
            int ybit = (iy >= YH) ? 1 : 0;
            float c0x = corners[0], c0z = corners[2];
            for (int r = 0; r < NROT; ++r) {
                int ix, iz;
                if (vote_xz(px, pz, ox, oz, rt.c[r], rt.s[r], c0x, c0z, ix, iz))
                    atomicAdd(&h[ix*2 + ybit], 1);
            }
        }
    }
    __syncthreads();
    for (int j = tid; j < NBINS; j += 256) if (h[j]) atomicAdd(&bincnt[j], h[j]);
}

// ---------------- K1b: prefix sum over bins ----------------
__global__ void k_prefix(const int* __restrict__ bincnt, int* __restrict__ binbase,
                         int* __restrict__ bincur) {
    if (threadIdx.x == 0 && blockIdx.x == 0) {
        int acc = 0;
        for (int b = 0; b < NBINS; ++b) {
            binbase[b] = acc;
            bincur[b] = acc;
            acc += bincnt[b];
        }
    }
}

// ---------------- K1c: write vote records binned ----------------
__global__ __launch_bounds__(256) void k_binwrite(const float* __restrict__ pc, const float* __restrict__ xyz,
                          const float* __restrict__ prob, const float* __restrict__ corners,
                          int N, RotTab rt, int* __restrict__ bincur,
                          int* __restrict__ vflat, float* __restrict__ vw) {
    __shared__ int h[NBINS];
    __shared__ int bbase[NBINS];
    int tid = threadIdx.x;
    for (int j = tid; j < NBINS; j += 256) h[j] = 0;
    __syncthreads();
    int i = blockIdx.x * 256 + tid;
    float px=0, py=0, pz=0, ox=0, oy=0, oz=0, w0=0, c0x=0, c0z=0;
    int iy = -1, ybit = 0;
    bool act = false;
    if (i < N) {
        px = pc[3*i]; py = pc[3*i+1]; pz = pc[3*i+2];
        ox = xyz[3*i]; oy = xyz[3*i+1]; oz = xyz[3*i+2];
        w0 = prob[i];
        c0x = corners[0]; c0z = corners[2];
        if (vote_iy(py, oy, corners[1], iy)) {
            act = true;
            ybit = (iy >= YH) ? 1 : 0;
        }
    }
    if (act) {
        for (int r = 0; r < NROT; ++r) {
            int ix, iz;
            if (vote_xz(px, pz, ox, oz, rt.c[r], rt.s[r], c0x, c0z, ix, iz))
                atomicAdd(&h[ix*2 + ybit], 1);
        }
    }
    __syncthreads();
    for (int j = tid; j < NBINS; j += 256) {
        int cnt = h[j];
        bbase[j] = cnt ? atomicAdd(&bincur[j], cnt) : 0;
        h[j] = 0;  // reuse as local cursor
    }
    __syncthreads();
    if (act) {
        for (int r = 0; r < NROT; ++r) {
            int ix, iz;
            if (vote_xz(px, pz, ox, oz, rt.c[r], rt.s[r], c0x, c0z, ix, iz)) {
                int bin = ix*2 + ybit;
                int rank = atomicAdd(&h[bin], 1);
                int slot = bbase[bin] + rank;
                vflat[slot] = (ix*GYD + iy)*GZD + iz;
                vw[slot] = w0;
            }
        }
    }
}

// ---------------- K1d: per-bin LDS accumulate -> gobj ----------------
__global__ __launch_bounds__(256) void k_accum(const int* __restrict__ binbase,
                          const int* __restrict__ bincnt,
                          const int* __restrict__ vflat, const float* __restrict__ vw,
                          float* __restrict__ gobj) {
    __shared__ float tile[YH*GZD];   // 56*272*4 = 60928 B
    int b = blockIdx.x;
    int x = b >> 1, yh = b & 1;
    int tid = threadIdx.x;
    for (int j = tid; j < YH*GZD; j += 256) tile[j] = 0.0f;
    __syncthreads();
    int lo = binbase[b], n = bincnt[b];
    int xoff = x * SLICE;
    int yoff = yh * (YH*GZD);
    for (int j = lo + tid; j < lo + n; j += 256) {
        int rel = vflat[j] - xoff;        // (iy*GZD + iz) within slice
        atomicAdd(&tile[rel - yoff], vw[j]);
    }
    __syncthreads();
    float* dst = gobj + (size_t)xoff + yoff;
    for (int j = tid; j < YH*GZD; j += 256) dst[j] = tile[j];
}

// ---------------- K2: per-(x,z) max/argmax over y; logits; sum(dist) ----------------
__global__ __launch_bounds__(256) void k_colmax(const float* __restrict__ gobj,
                         float* __restrict__ logits, int* __restrict__ yidx,
                         float* __restrict__ sumdist) {
    int c = blockIdx.x * blockDim.x + threadIdx.x;
    float d = 0.0f;
    if (c < CCLS) {
        int x = c / GZD, z = c % GZD;
        const float* base = gobj + (size_t)x*GYD*GZD + z;
        float m = base[0];
        int mi = 0;
        for (int y = 1; y < GYD; ++y) {
            float v = base[(size_t)y*GZD];
            if (v > m) { m = v; mi = y; }  // strict > => first occurrence
        }
        d = __fsqrt_rn(__fadd_rn(m, 1e-7f));
        yidx[c] = mi;
        logits[c] = (float)log((double)__fadd_rn(d, 1e-30f));
    }
    __shared__ float sred[256];
    int tid = threadIdx.x;
    sred[tid] = d; __syncthreads();
    for (int off = 128; off > 0; off >>= 1) {
        if (tid < off) sred[tid] += sred[tid+off];
        __syncthreads();
    }
    if (tid == 0) atomicAdd(sumdist, sred[0]);
}

// ---------------- K2b: per-column integer bits-threshold ----------------
// survivor v = gumbel(u)+L > B0  <=>  u > u* = exp(-exp(L-B0)).  u = (bits>>9)*2^-23
// (monotone in bits).  Store bth = (floor(u*·2^23)-2)<<9: test (bits >= bth) can
// only OVER-include vs the exact condition (margin 2 mantissa steps + 0.05 in B0).
__global__ __launch_bounds__(256) void k_thresh(const float* __restrict__ logits,
                                                const float* __restrict__ sumdist,
                                                uint32_t* __restrict__ bth) {
    int c = blockIdx.x * blockDim.x + threadIdx.x;
    if (c >= CCLS) return;
    double B0 = log((double)*sumdist) - 3.0;
    double t = exp(-exp((double)logits[c] - (B0 - 0.05)));
    long long k_th = (long long)floor(t * 8388608.0) - 2;
    uint32_t b;
    if (k_th <= 0)              b = 0u;           // everything survives
    else if (k_th >= 8388608LL) b = 0xFFFFFFFFu;  // ~nothing survives (over-include, harmless)
    else                        b = (uint32_t)k_th << 9;
    bth[c] = b;
}

// ---------------- K3: categorical sampling — integer prefilter + exact eval ----------------
__global__ __launch_bounds__(256) void k_sample(const float* __restrict__ logits,
                                                const uint32_t* __restrict__ bth,
                                                float* __restrict__ pval,
                                                int* __restrict__ pidx) {
    int half = blockIdx.x;
    int k = blockIdx.y;
    int tid = threadIdx.x;
    int cstart = half * HCOLS;
    uint32_t base = (uint32_t)k * (uint32_t)CCLS + (uint32_t)cstart;

    __shared__ int cnt;
    __shared__ int      svc[SCAP];
    __shared__ uint32_t svb[SCAP];
    __shared__ float sv[256];
    __shared__ int   si[256];
    if (tid == 0) cnt = 0;
    __syncthreads();

    const uint4* bt4 = (const uint4*)(bth + cstart);
    for (int q = tid; q < HCOLS/4; q += 256) {
        int j0 = q * 4;
        uint4 bt = bt4[q];
        uint32_t b0 = tf_bits(base + (uint32_t)j0);
        uint32_t b1 = tf_bits(base + (uint32_t)j0 + 1u);
        uint32_t b2 = tf_bits(base + (uint32_t)j0 + 2u);
        uint32_t b3 = tf_bits(base + (uint32_t)j0 + 3u);
        bool h0 = b0 >= bt.x, h1 = b1 >= bt.y, h2 = b2 >= bt.z, h3 = b3 >= bt.w;
        if (__builtin_expect(h0 | h1 | h2 | h3, 0)) {
            if (h0) { int idx = atomicAdd(&cnt, 1); if (idx < SCAP) { svc[idx] = cstart + j0;     svb[idx] = b0; } }
            if (h1) { int idx = atomicAdd(&cnt, 1); if (idx < SCAP) { svc[idx] = cstart + j0 + 1; svb[idx] = b1; } }
            if (h2) { int idx = atomicAdd(&cnt, 1); if (idx < SCAP) { svc[idx] = cstart + j0 + 2; svb[idx] = b2; } }
            if (h3) { int idx = atomicAdd(&cnt, 1); if (idx < SCAP) { svc[idx] = cstart + j0 + 3; svb[idx] = b3; } }
        }
    }
    __syncthreads();

    int n = cnt;
    float best = -INFINITY; int bc = 0x7fffffff;
    if (n > 0 && n <= SCAP) {
        for (int j = tid; j < n; j += 256) {
            int c = svc[j];
            float v = __fadd_rn(gumbel_from_u(uniform_from_bits(svb[j])), logits[c]);
            if (v > best || (v == best && c < bc)) { best = v; bc = c; }
        }
    } else {
        // empty (all v <= B0-cut in range) or overflow: exact full scan of range
        for (int j = tid; j < HCOLS; j += 256) {
            int c = cstart + j;
            float v = __fadd_rn(gumbel_from_u(uniform_from_bits(tf_bits(base + (uint32_t)j))), logits[c]);
            if (v > best || (v == best && c < bc)) { best = v; bc = c; }
        }
    }
    sv[tid] = best; si[tid] = bc; __syncthreads();
    for (int off = 128; off > 0; off >>= 1) {
        if (tid < off) {
            float v2 = sv[tid+off]; int i2 = si[tid+off];
            if (v2 > sv[tid] || (v2 == sv[tid] && i2 < si[tid])) { sv[tid] = v2; si[tid] = i2; }
        }
        __syncthreads();
    }
    if (tid == 0) { pval[2*k + half] = sv[0]; pidx[2*k + half] = si[0]; }
}

// ---------------- K3m: merge halves ----------------
__global__ void k_merge(const float* __restrict__ pval, const int* __restrict__ pidx,
                        int* __restrict__ samples) {
    int k = blockIdx.x * blockDim.x + threadIdx.x;
    if (k >= KSMP) return;
    float v0 = pval[2*k], v1 = pval[2*k+1];
    // half0 columns are all lower-indexed than half1's -> ties go to half0
    samples[k] = (v1 > v0) ? pidx[2*k+1] : pidx[2*k];
}

// ---------------- K3b: build sampled-cell hash table (single block) ----------------
__global__ __launch_bounds__(256) void k_build_table(const int* __restrict__ samples,
                                                     const int* __restrict__ yidx,
                                                     int* __restrict__ hkeys,
                                                     float* __restrict__ gsmall) {
    int tid = threadIdx.x;
    for (int j = tid; j < HSLOTS; j += 256) hkeys[j] = -1;
    for (int j = tid; j < 3*HSLOTS; j += 256) gsmall[j] = 0.0f;
    __syncthreads();
    for (int k = tid; k < KSMP; k += 256) {
        int s = samples[k];
        int xi = s / GZD, zi = s % GZD;
        int yi = yidx[s];
        int flat = (xi*GYD + yi)*GZD + zi;
        uint32_t h = cell_hash(flat);
        for (;;) {
            int prev = atomicCAS(&hkeys[h], -1, flat);
            if (prev == -1 || prev == flat) break;
            h = (h + 1) & (HSLOTS - 1);
        }
    }
}

// ---------------- K3c: replay votes, accumulate scale sums at sampled cells ----------------
__global__ __launch_bounds__(256) void k_scale_scatter(const float* __restrict__ pc, const float* __restrict__ xyz,
                          const float* __restrict__ scale, const float* __restrict__ prob,
                          const float* __restrict__ corners,
                          const int* __restrict__ hkeys, float* __restrict__ gsmall,
                          int N, RotTab rt) {
    __shared__ int lk[HSLOTS];
    for (int j = threadIdx.x; j < HSLOTS; j += 256) lk[j] = hkeys[j];
    __syncthreads();
    int i = blockIdx.x * blockDim.x + threadIdx.x;
    int r = blockIdx.y;
    if (i >= N) return;
    int flat;
    if (!vote_cell(pc[3*i], pc[3*i+1], pc[3*i+2], xyz[3*i], xyz[3*i+1], xyz[3*i+2],
                   rt.c[r], rt.s[r], corners[0], corners[1], corners[2], flat)) return;
    uint32_t h = cell_hash(flat);
    int slot = -1;
    for (;;) {
        int key = lk[h];
        if (key == flat) { slot = (int)h; break; }
        if (key == -1) break;
        h = (h + 1) & (HSLOTS - 1);
    }
    if (slot < 0) return;
    float w0 = prob[i];
    atomicAdd(&gsmall[3*slot+0], __fmul_rn(w0, scale[3*i]));
    atomicAdd(&gsmall[3*slot+1], __fmul_rn(w0, scale[3*i+1]));
    atomicAdd(&gsmall[3*slot+2], __fmul_rn(w0, scale[3*i+2]));
}

// ---------------- K4: one block per sample — world loc, scale, keep ----------------
__global__ __launch_bounds__(256) void k_post(const float* __restrict__ gobj,
                       const int* __restrict__ hkeys, const float* __restrict__ gsmall,
                       const int* __restrict__ yidx, const int* __restrict__ samples,
                       const float* __restrict__ corners, const float* __restrict__ vp, int M,
                       float* __restrict__ world, float* __restrict__ scv, int* __restrict__ keep) {
    int k = blockIdx.x;
    int tid = threadIdx.x;
    int s = samples[k];
    int xi = s / GZD, zi = s % GZD;
    int yi = yidx[s];
    float wx = __fadd_rn(__fmul_rn((float)xi, 0.03f), corners[0]);
    float wy = __fadd_rn(__fmul_rn((float)yi, 0.03f), corners[1]);
    float wz = __fadd_rn(__fmul_rn((float)zi, 0.03f), corners[2]);

    float dmin = INFINITY;
    for (int j = tid; j < M; j += 256) {
        float dx = __fsub_rn(wx, vp[3*j]);
        float dy = __fsub_rn(wy, vp[3*j+1]);
        float dz = __fsub_rn(wz, vp[3*j+2]);
        float sq = __fadd_rn(__fadd_rn(__fmul_rn(dx,dx), __fmul_rn(dy,dy)), __fmul_rn(dz,dz));
        dmin = fminf(dmin, __fsqrt_rn(sq));
    }
    __shared__ float sm[256];
    sm[tid] = dmin; __syncthreads();
    for (int off = 128; off > 0; off >>= 1) {
        if (tid < off) sm[tid] = fminf(sm[tid], sm[tid+off]);
        __syncthreads();
    }
    if (tid == 0) {
        world[3*k] = wx; world[3*k+1] = wy; world[3*k+2] = wz;
        int flat = (xi*GYD + yi)*GZD + zi;
        uint32_t h = cell_hash(flat);
        while (hkeys[h] != flat) h = (h + 1) & (HSLOTS - 1);  // guaranteed present
        float go = __fadd_rn(gobj[flat], 1e-7f);
        scv[3*k+0] = __fdiv_rn(gsmall[3*h+0], go);
        scv[3*k+1] = __fdiv_rn(gsmall[3*h+1], go);
        scv[3*k+2] = __fdiv_rn(gsmall[3*h+2], go);
        keep[k] = (sm[0] < 0.3f) ? 1 : 0;
    }
}

// ---------------- K5: stable 0/1 selection + output write ----------------
__global__ __launch_bounds__(256) void k_select(const float* __restrict__ world,
                                                const float* __restrict__ scv,
                                                const int* __restrict__ keep,
                                                float* __restrict__ out) {
    __shared__ int kp[KSMP];
    __shared__ int sel[NPROP];
    int tid = threadIdx.x;
    for (int j = tid; j < KSMP; j += 256) kp[j] = keep[j];
    __syncthreads();
    if (tid == 0) {
        int any = 0;
        for (int j = 0; j < KSMP; ++j) any |= kp[j];
        int cnt = 0;
        if (any) {
            for (int j = 0; j < KSMP && cnt < NPROP; ++j) if (kp[j])  sel[cnt++] = j;
            for (int j = 0; j < KSMP && cnt < NPROP; ++j) if (!kp[j]) sel[cnt++] = j;
        } else {
            for (int j = 0; j < NPROP; ++j) sel[j] = j;  // argsort(zeros) stable = identity
        }
    }
    __syncthreads();
    if (tid < NPROP) {
        int sidx = sel[tid];
        out[3*tid+0] = world[3*sidx+0];
        out[3*tid+1] = world[3*sidx+1];
        out[3*tid+2] = world[3*sidx+2];
        out[3*NPROP + tid] = 0.0f;                 // probs
        out[4*NPROP + 3*tid + 0] = scv[3*sidx+0];
        out[4*NPROP + 3*tid + 1] = scv[3*sidx+1];
        out[4*NPROP + 3*tid + 2] = scv[3*sidx+2];
    }
}

extern "C" void kernel_launch(void* const* d_in, const int* in_sizes, int n_in,
                              void* d_out, int out_size, void* d_ws, size_t ws_size,
                              hipStream_t stream) {
    const float* pc      = (const float*)d_in[0];
    const float* xyz     = (const float*)d_in[1];
    const float* scale   = (const float*)d_in[2];
    const float* prob    = (const float*)d_in[3];
    const float* corners = (const float*)d_in[4];
    const float* vp      = (const float*)d_in[5];
    int N = in_sizes[0] / 3;
    int M = in_sizes[5] / 3;
    int NV = N * NROT;

    const size_t G = (size_t)GXD * GYD * GZD;  // 8,286,208
    float* gobj    = (float*)d_ws;
    float* sumdist = gobj + G;          // 1 float — zeroed by memset below
    int*   bincnt  = (int*)(sumdist + 1);   // NBINS — zeroed by memset below
    int*   binbase = bincnt + NBINS;
    int*   bincur  = binbase + NBINS;
    float* logits  = (float*)(bincur + NBINS);
    uint32_t* bth  = (uint32_t*)(logits + CCLS);
    int*   yidx    = (int*)(bth + CCLS);
    float* pval    = (float*)(yidx + CCLS);
    int*   pidx    = (int*)(pval + 2*KSMP);
    int*   samples = pidx + 2*KSMP;
    int*   hkeys   = samples + KSMP;
    float* gsmall  = (float*)(hkeys + HSLOTS);
    float* world   = gsmall + 3*HSLOTS;
    float* scv     = world + 3*KSMP;
    int*   keep    = (int*)(scv + 3*KSMP);
    int*   vflat   = keep + KSMP;
    float* vw      = (float*)(vflat + NV);
    size_t need = (size_t)((char*)(vw + NV) - (char*)d_ws);
    if (ws_size < need) {
        fprintf(stderr, "kernel_launch: ws_size %zu < needed %zu\n", ws_size, need);
        return;
    }

    // zero sumdist + bincnt only (gobj fully written by k_accum)
    hipMemsetAsync(sumdist, 0, (1 + NBINS)*sizeof(int), stream);

    // rotation table: f32 theta chain exactly as reference, cos/sin in double -> f32
    RotTab rt;
    const float twopi = (float)(2.0 * M_PI);
    for (int r = 0; r < NROT; ++r) {
        float th = (twopi * (float)r) / 36.0f;
        rt.c[r] = (float)cos((double)th);
        rt.s[r] = (float)sin((double)th);
    }

    int pblocks = (N + 255) / 256;
    k_count<<<pblocks, 256, 0, stream>>>(pc, xyz, corners, N, rt, bincnt);
    k_prefix<<<1, 64, 0, stream>>>(bincnt, binbase, bincur);
    k_binwrite<<<pblocks, 256, 0, stream>>>(pc, xyz, prob, corners, N, rt, bincur, vflat, vw);
    k_accum<<<NBINS, 256, 0, stream>>>(binbase, bincnt, vflat, vw, gobj);
    k_colmax<<<(CCLS + 255) / 256, 256, 0, stream>>>(gobj, logits, yidx, sumdist);
    k_thresh<<<(CCLS + 255) / 256, 256, 0, stream>>>(logits, sumdist, bth);
    dim3 samp_grid(2, KSMP);
    k_sample<<<samp_grid, 256, 0, stream>>>(logits, bth, pval, pidx);
    k_merge<<<(KSMP + 255) / 256, 256, 0, stream>>>(pval, pidx, samples);
    k_build_table<<<1, 256, 0, stream>>>(samples, yidx, hkeys, gsmall);
    dim3 sgrid(pblocks, NROT);
    k_scale_scatter<<<sgrid, 256, 0, stream>>>(pc, xyz, scale, prob, corners, hkeys, gsmall, N, rt);
    k_post<<<KSMP, 256, 0, stream>>>(gobj, hkeys, gsmall, yidx, samples, corners, vp, M, world, scv, keep);
    k_select<<<1, 256, 0, stream>>>(world, scv, keep, (float*)d_out);
}